// Round 3
// baseline (425.015 us; speedup 1.0000x reference)
//
#include <hip/hip_runtime.h>
#include <stdint.h>

#define B_  16
#define C_  256
#define HW_ 4096
#define Hp  66
#define PP  4356   // 66*66
#define EPS_ 1e-5f

typedef unsigned short u16;
typedef unsigned int   u32;
typedef __attribute__((ext_vector_type(4))) float  f32x4;
typedef __attribute__((ext_vector_type(8))) __bf16 bf16x8;
typedef __attribute__((ext_vector_type(8))) u16    u16x8;

__device__ __forceinline__ float bf2f(u16 u){ u32 x = ((u32)u)<<16; float f; __builtin_memcpy(&f,&x,4); return f; }
__device__ __forceinline__ u16 f2bf(float f){ u32 x; __builtin_memcpy(&x,&f,4); u32 r = x + 0x7fffu + ((x>>16)&1u); return (u16)(r>>16); }

__device__ __forceinline__ void g2l16(const void* g, void* l){
  __builtin_amdgcn_global_load_lds((__attribute__((address_space(1))) void*)(void*)g,
                                   (__attribute__((address_space(3))) void*)l, 16, 0, 0);
}
__device__ __forceinline__ bf16x8 ldfrag(const u16* p){
  u16x8 r = *(const u16x8*)p;
  return __builtin_bit_cast(bf16x8, r);
}

// ---------------- K0: pad+transpose x AND repack weights (merged, block-range split) -----
// Layouts (conflict-free atom-major LDS staging for k_conv):
//   xpT: [b][ci(8)][atom(4)][PP pixels][8ch]
//   wBt: [ci(8)][tap(9)][atom(4)][co(256)][8ch]
__global__ __launch_bounds__(256) void k_prep(const float* __restrict__ x, u16* __restrict__ xpT,
    const float* __restrict__ conv_w, const float* __restrict__ wq, const float* __restrict__ wo,
    const float* __restrict__ wk, const float* __restrict__ wv, const float* __restrict__ ctx,
    u16* __restrict__ wBt, u16* __restrict__ wqB, u16* __restrict__ woB,
    u16* __restrict__ wkvB, u16* __restrict__ ctxB, float* __restrict__ stats){
  __shared__ float Lt[64*65];
  int bid = blockIdx.x; int tid = threadIdx.x;
  if(bid >= 1056){
    int i = (bid-1056)*256 + tid;
    if(i < 589824){
      // wBt[((cic*9+t)*4+atom)*2048 + co*8 + j] = conv_w[co][cic*32+atom*8+j][t]
      int j = i&7, co = (i>>3)&255, atom = (i>>11)&3, g = i>>13;   // g in [0,72)
      int t = g%9, cic = g/9;
      int ciF = cic*32 + atom*8 + j;
      wBt[i] = f2bf(conv_w[(co*256+ciF)*9 + t]); return;
    }
    i -= 589824;
    if(i < 65536){ wqB[i] = f2bf(wq[i]); return; } i -= 65536;
    if(i < 65536){ woB[i] = f2bf(wo[i]); return; } i -= 65536;
    if(i < 196608){ wkvB[i] = f2bf(wk[i]); return; } i -= 196608;
    if(i < 196608){ wkvB[196608+i] = f2bf(wv[i]); return; } i -= 196608;
    if(i < 946176){ ctxB[i] = f2bf(ctx[i]); return; } i -= 946176;
    if(i < 512){ stats[i] = 0.f; }
    return;
  }
  int b = bid/66, hh = bid - b*66;
  if(hh==0 || hh==65){
    // zero full padded row: 66 pixels x 8ch across 32 (ci,atom) planes
    for(int i=tid;i<32*264;i+=256){
      int pl = i/264, off = i - pl*264;   // off in u32 units (264 u32 = 528 u16 = 66*8)
      u32* p = (u32*)(xpT + ((size_t)(b*32+pl)*PP + (size_t)hh*Hp)*8);
      p[off] = 0u;
    }
    return;
  }
  {
    // zero ww=0 and ww=65 borders for this row: 32 planes x (2 pixels x 4 u32)
    int pl = tid>>3, q = tid&7;
    size_t base = ((size_t)(b*32+pl)*PP + (size_t)hh*Hp + (q>=4?65:0))*8;
    ((u32*)(xpT + base))[q&3] = 0u;
  }
  int h = hh-1;
  for(int cc=0; cc<4; cc++){
    int c0=cc*64;
    int ci = tid>>2, w0 = (tid&3)*16;
    const float* xs = x + ((size_t)(b*C_ + c0+ci)*HW_) + h*64 + w0;
    for(int j=0;j<4;j++){
      float4 v = *(const float4*)(xs + j*4);
      Lt[ci*65 + w0 + j*4 + 0] = v.x;
      Lt[ci*65 + w0 + j*4 + 1] = v.y;
      Lt[ci*65 + w0 + j*4 + 2] = v.z;
      Lt[ci*65 + w0 + j*4 + 3] = v.w;
    }
    __syncthreads();
    int w = tid>>2, cj = (tid&3)*16;
    union { u16 u[16]; uint4 v[2]; } outu;
    for(int j=0;j<16;j++) outu.u[j] = f2bf(Lt[(cj+j)*65 + w]);
    int chan = c0 + cj;
    int cic = chan>>5, at0 = (chan>>3)&3;
    u16* dst = xpT + (((size_t)(b*8+cic)*4 + at0)*PP + (size_t)hh*Hp + w + 1)*8;
    *(uint4*)dst = outu.v[0];
    *(uint4*)(dst + (size_t)PP*8) = outu.v[1];
    __syncthreads();
  }
}

// ---------------- K2: conv implicit GEMM, counted-vmcnt pipeline (T4) ----------------
// 512 blocks, 128 px x 256 ch, acc[4][8]. Double-buffered As/Bs (66.5KB, 2 blocks/CU).
// Raw s_barrier + inline-asm counted s_waitcnt: A-prefetch (1 g2l16/thread, taps 0-3,
// uniform thanks to LDS-zeroed w-halo columns) stays in flight across barriers
// (vmcnt(1)); B (L2-resident) covered by the MFMA phase (vmcnt(0)).
__global__ __launch_bounds__(256, 2) void k_conv(const u16* __restrict__ xpT, const u16* __restrict__ wBt,
    const float* __restrict__ conv_b, u16* __restrict__ h, float* __restrict__ stats){
  __shared__ u16 As[2][264*32];   // [buf][atom(4)][264 px][8ch] = 16,896 B each
  __shared__ u16 Bs[2][256*32];   // [buf][atom(4)][256 co][8ch] = 16,384 B each
  int bid = blockIdx.x;
  int b = bid >> 5, hp = bid & 31;
  int tid = threadIdx.x;
  int w = tid>>6, lane = tid&63, ln = lane&15, qd = lane>>4;
  int wm = w&1, wn = w>>1;
  f32x4 acc[4][8] = {};
  int hr_[4], wp_[4];
  #pragma unroll
  for(int mf=0;mf<4;mf++){ int p = wm*64 + mf*16 + ln; hr_[mf] = p>>6; wp_[mf] = p&63; }
  int arow = tid>>6, apx = tid&63;   // per-thread A-staging coords (row = wave id, px = lane)

  // zero the w-halo columns (px 0 and 65 of each of the 4 rows) in BOTH buffers, once
  if(tid < 64){
    int buf = tid>>5, k = tid&31;
    int atom = k>>3, row = (k>>1)&3, side = k&1;
    uint4 z = {0,0,0,0};
    *(uint4*)&As[buf][(atom*264 + row*66 + side*65)*8] = z;
  }

  // prologue: B(step 0) then A(ci=0) (FIFO order: B older than A)
  #pragma unroll
  for(int r=0;r<4;r++)
    g2l16(wBt + ((size_t)0*1024 + r*256 + tid)*8, &Bs[0][(r*256+tid)*8]);
  #pragma unroll
  for(int r=0;r<4;r++)
    g2l16(xpT + (((size_t)(b*8+0)*4 + r)*PP + hp*132 + arow*66 + 1 + apx)*8,
          &As[0][(r*264 + arow*66 + 1 + apx)*8]);
  __syncthreads();   // full drain once; after this, counted waits only

  for(int ci=0; ci<8; ci++){
    int ab = ci&1;
    int cin = ci<7 ? ci+1 : 7;     // ci=7: dummy re-read of own slab (keeps counts uniform)
    for(int t=0;t<9;t++){
      int pb = (ci + t)&1;         // B buffer parity for this step (9 odd => ci*9 ~ ci)
      int last = (ci==7) & (t==8);
      // issue next-step B tile into pb^1
      if(!last){
        int tn = t+1, cb2 = ci; if(tn==9){tn=0; cb2=ci+1;}
        int g = cb2*9 + tn;
        #pragma unroll
        for(int r=0;r<4;r++)
          g2l16(wBt + ((size_t)g*1024 + r*256 + tid)*8, &Bs[pb^1][(r*256+tid)*8]);
      }
      // issue one A quarter (atom=t) for next ci, AFTER B (newer in FIFO)
      if(t<4)
        g2l16(xpT + (((size_t)(b*8+cin)*4 + t)*PP + hp*132 + arow*66 + 1 + apx)*8,
              &As[ab^1][(t*264 + arow*66 + 1 + apx)*8]);

      int dy = (t*11)>>5, dx = t - dy*3;
      bf16x8 af[4], bfv[8];
      #pragma unroll
      for(int mf=0;mf<4;mf++){
        int ipix = (hr_[mf]+dy)*66 + wp_[mf] + dx;
        af[mf] = ldfrag(&As[ab][(qd*264 + ipix)*8]);
      }
      #pragma unroll
      for(int nf=0;nf<8;nf++) bfv[nf] = ldfrag(&Bs[pb][(qd*256 + wn*128+nf*16+ln)*8]);
      #pragma unroll
      for(int mf=0;mf<4;mf++)
        #pragma unroll
        for(int nf=0;nf<8;nf++)
          acc[mf][nf] = __builtin_amdgcn_mfma_f32_16x16x32_bf16(af[mf], bfv[nf], acc[mf][nf], 0,0,0);

      if(!last){
        // keep this step's A chunk (newest, 1) in flight; drain everything older
        if(t<4) asm volatile("s_waitcnt vmcnt(1)" ::: "memory");
        else    asm volatile("s_waitcnt vmcnt(0)" ::: "memory");
        __builtin_amdgcn_s_barrier();
      }
    }
  }

  float s[4]={0,0,0,0}, q[4]={0,0,0,0};
  int p0 = hp*128;
  for(int nf=0;nf<8;nf++){
    int n = wn*128 + nf*16 + ln;
    float bias = conv_b[n];
    for(int mf=0;mf<4;mf++){
      for(int r=0;r<4;r++){
        int p = wm*64 + mf*16 + qd*4 + r;
        float v = acc[mf][nf][r] + bias;
        h[((size_t)(b*HW_ + p0 + p))*C_ + n] = f2bf(v);
        s[nf>>1]+=v; q[nf>>1]+=v*v;
      }
    }
  }
  for(int off=32;off>=1;off>>=1){
    #pragma unroll
    for(int g=0;g<4;g++){ s[g]+=__shfl_down(s[g],off,64); q[g]+=__shfl_down(q[g],off,64); }
  }
  if(lane==0){
    #pragma unroll
    for(int g=0;g<4;g++){
      atomicAdd(&stats[(b*8 + wn*4 + g)*2+0], s[g]);
      atomicAdd(&stats[(b*8 + wn*4 + g)*2+1], q[g]);
    }
  }
}

// ---------------- K5: fused GN+SiLU+qproj: q = silu(gn(h)) @ wq^T + bq ----------------
__global__ __launch_bounds__(256, 2) void k_qgn(const u16* __restrict__ hbuf, const u16* __restrict__ wqB,
    const float* __restrict__ stats, const float* __restrict__ gnw, const float* __restrict__ gnb,
    const float* __restrict__ bq, u16* __restrict__ qb){
  __shared__ u16 As[128*32];
  __shared__ u16 Bs[256*32];
  int mt = blockIdx.x;
  int b = mt >> 5;
  int tid = threadIdx.x;
  int w = tid>>6, lane = tid&63, ln = lane&15, qd = lane>>4;
  int wm = w&1, wn = w>>1;
  int pr = tid>>1, half = tid&1;
  const u16* hsrc = hbuf + ((size_t)(mt*128+pr))*256 + half*16;
  f32x4 acc[4][8] = {};
  uint4 ra0, ra1, rb0, rb1;
  ra0 = *(const uint4*)(hsrc);
  ra1 = *(const uint4*)(hsrc + 8);
  for(int kt=0; kt<8; kt++){
    float sm = stats[(b*8+kt)*2], qm = stats[(b*8+kt)*2+1];
    float mean = sm*(1.f/131072.f);
    float rstd = rsqrtf(qm*(1.f/131072.f) - mean*mean + EPS_);
    int c0 = kt*32 + half*16;
    float4 gw0 = *(const float4*)(gnw+c0), gw1 = *(const float4*)(gnw+c0+4);
    float4 gw2 = *(const float4*)(gnw+c0+8), gw3 = *(const float4*)(gnw+c0+12);
    float4 gb0 = *(const float4*)(gnb+c0), gb1 = *(const float4*)(gnb+c0+4);
    float4 gb2 = *(const float4*)(gnb+c0+8), gb3 = *(const float4*)(gnb+c0+12);
    float gwv[16] = {gw0.x,gw0.y,gw0.z,gw0.w, gw1.x,gw1.y,gw1.z,gw1.w,
                     gw2.x,gw2.y,gw2.z,gw2.w, gw3.x,gw3.y,gw3.z,gw3.w};
    float gbv[16] = {gb0.x,gb0.y,gb0.z,gb0.w, gb1.x,gb1.y,gb1.z,gb1.w,
                     gb2.x,gb2.y,gb2.z,gb2.w, gb3.x,gb3.y,gb3.z,gb3.w};
    u16 inu[16];
    ((uint4*)inu)[0] = ra0; ((uint4*)inu)[1] = ra1;
    u16 outu[16];
    #pragma unroll
    for(int j=0;j<16;j++){
      float v = bf2f(inu[j]);
      v = (v-mean)*rstd*gwv[j] + gbv[j];
      float s = v/(1.f+__expf(-v));
      outu[j] = f2bf(s);
    }
    u16* adst = &As[pr*32 + half*16];
    ((uint4*)adst)[0] = ((uint4*)outu)[0];
    ((uint4*)adst)[1] = ((uint4*)outu)[1];
    #pragma unroll
    for(int r=0;r<4;r++){
      int c = r*256 + tid;
      int co = c>>2, atom = c&3;
      g2l16(wqB + (size_t)co*256 + kt*32 + atom*8, &Bs[c*8]);
    }
    if(kt<7){
      rb0 = *(const uint4*)(hsrc + (kt+1)*32);
      rb1 = *(const uint4*)(hsrc + (kt+1)*32 + 8);
    }
    __syncthreads();
    bf16x8 af[4], bfv[8];
    #pragma unroll
    for(int mf=0;mf<4;mf++) af[mf] = ldfrag(&As[(wm*64+mf*16+ln)*32 + qd*8]);
    #pragma unroll
    for(int nf=0;nf<8;nf++) bfv[nf] = ldfrag(&Bs[(wn*128+nf*16+ln)*32 + qd*8]);
    #pragma unroll
    for(int mf=0;mf<4;mf++)
      #pragma unroll
      for(int nf=0;nf<8;nf++)
        acc[mf][nf] = __builtin_amdgcn_mfma_f32_16x16x32_bf16(af[mf], bfv[nf], acc[mf][nf], 0,0,0);
    __syncthreads();
    ra0 = rb0; ra1 = rb1;
  }
  for(int nf=0;nf<8;nf++){
    int n = wn*128 + nf*16 + ln;
    float bias = bq[n];
    for(int mf=0;mf<4;mf++){
      for(int r=0;r<4;r++){
        int ml = wm*64 + mf*16 + qd*4 + r;
        qb[((size_t)(mt*128+ml))*256 + n] = f2bf(acc[mf][nf][r]+bias);
      }
    }
  }
}

// ---------------- K6: k,v = ctx @ {wk,wv}^T + b, 64x64 tiles, 160 blocks ----------------
__global__ __launch_bounds__(256) void k_kvproj(const u16* __restrict__ ctxB, const u16* __restrict__ wkvB,
    const float* __restrict__ bk, const float* __restrict__ bv,
    u16* __restrict__ kb, u16* __restrict__ vT){
  __shared__ u16 As[64*128];
  __shared__ u16 Bs[64*128];
  int bid = blockIdx.x;
  int nt = bid & 7, mt = bid >> 3;
  int n0 = nt*64, m0 = mt*64;
  int tid=threadIdx.x, w=tid>>6, lane=tid&63, ln=lane&15, qd=lane>>4;
  int wm = w&1, wn = w>>1;
  f32x4 acc[2][2]={};
  for(int kt=0;kt<6;kt++){
    #pragma unroll
    for(int r=0;r<4;r++){
      int c = r*256 + tid;
      int row = c>>4, atom = c&15;
      g2l16(ctxB + ((size_t)(m0+row)*768 + kt*128 + atom*8), &As[c*8]);
      g2l16(wkvB + ((size_t)(n0+row)*768 + kt*128 + atom*8), &Bs[c*8]);
    }
    __syncthreads();
    #pragma unroll
    for(int kk=0;kk<4;kk++){
      bf16x8 af[2], bfv[2];
      #pragma unroll
      for(int mf=0;mf<2;mf++) af[mf]=ldfrag(&As[(wm*32+mf*16+ln)*128 + kk*32 + qd*8]);
      #pragma unroll
      for(int nf=0;nf<2;nf++) bfv[nf]=ldfrag(&Bs[(wn*32+nf*16+ln)*128 + kk*32 + qd*8]);
      #pragma unroll
      for(int mf=0;mf<2;mf++)
        #pragma unroll
        for(int nf=0;nf<2;nf++)
          acc[mf][nf]=__builtin_amdgcn_mfma_f32_16x16x32_bf16(af[mf],bfv[nf],acc[mf][nf],0,0,0);
    }
    __syncthreads();
  }
  for(int mf=0;mf<2;mf++) for(int nf=0;nf<2;nf++){
    int ng = n0 + wn*32 + nf*16 + ln;
    float bias = ng<256 ? bk[ng] : bv[ng-256];
    for(int r=0;r<4;r++){
      int mg = m0 + wm*32 + mf*16 + qd*4 + r;
      if(mg<1232){
        float v=acc[mf][nf][r]+bias;
        int bb=mg/77, l=mg-bb*77;
        if(ng<256) kb[((size_t)(bb*77+l))*256+ng]=f2bf(v);
        else vT[((size_t)(bb*256+(ng-256)))*96 + l]=f2bf(v);
      }
    }
  }
}

// ---------------- K7: attention per (b, 128-pixel q tile) ----------------
__global__ __launch_bounds__(256) void k_attn(const u16* __restrict__ qg, const u16* __restrict__ kb,
    const u16* __restrict__ vT, u16* __restrict__ ob){
  __shared__ u16 Qs[4096];        // 128 x 32
  __shared__ u16 KVs[4096];       // up to 128 x 32
  __shared__ u16 Sb[128*88];      // S scores, bf16, 88-stride
  __shared__ u16 Pb[128*104];     // P (unnormalized), bf16, k-padded to 96 (+8)
  __shared__ float invr[128];
  int bid=blockIdx.x; int b=bid>>5, qt=bid&31; int p0=qt*128;
  int tid=threadIdx.x, w=tid>>6, lane=tid&63, ln=lane&15, qd=lane>>4;
  int srow=tid>>2, koff=(tid&3)*8;
  f32x4 Sa[2][5]={};
  for(int kt=0;kt<8;kt++){
    for(int j=0;j<2;j++){
      int m=srow+j*64;
      g2l16(qg + ((size_t)(b*HW_+p0+m)*256 + kt*32+koff), &Qs[(size_t)tid*8+j*2048]);
    }
    for(int j=0;j<2;j++){
      int cja = tid + j*256;
      if(cja < 320){
        int l = cja>>2, ko2=(cja&3)*8;
        g2l16(kb + ((size_t)(b*77+l)*256 + kt*32+ko2), &KVs[(size_t)cja*8]);
      }
    }
    __syncthreads();
    bf16x8 af[2], bfv[5];
    for(int mf=0;mf<2;mf++) af[mf]=ldfrag(&Qs[(w*32+mf*16+ln)*32+qd*8]);
    for(int nf=0;nf<5;nf++) bfv[nf]=ldfrag(&KVs[(nf*16+ln)*32+qd*8]);
    for(int mf=0;mf<2;mf++) for(int nf=0;nf<5;nf++)
      Sa[mf][nf]=__builtin_amdgcn_mfma_f32_16x16x32_bf16(af[mf],bfv[nf],Sa[mf][nf],0,0,0);
    __syncthreads();
  }
  for(int mf=0;mf<2;mf++) for(int nf=0;nf<5;nf++) for(int r=0;r<4;r++){
    int ml=w*32+mf*16+qd*4+r, nl=nf*16+ln;
    Sb[ml*88+nl]=f2bf(Sa[mf][nf][r]*0.0625f);
  }
  __syncthreads();
  if(tid<128){
    u16* srp = &Sb[tid*88];
    srp[77]=0xFF80u; srp[78]=0xFF80u; srp[79]=0xFF80u;   // -inf tail pad
    float mx=-1e30f;
    #pragma unroll
    for(int c8=0;c8<10;c8++){
      u16x8 v = *(const u16x8*)(srp + c8*8);
      #pragma unroll
      for(int j=0;j<8;j++) mx = fmaxf(mx, bf2f(v[j]));
    }
    u16* prow = &Pb[tid*104];
    float sum=0.f;
    #pragma unroll
    for(int c8=0;c8<10;c8++){
      u16x8 v = *(const u16x8*)(srp + c8*8);
      u16x8 o;
      #pragma unroll
      for(int j=0;j<8;j++){ float e=__expf(bf2f(v[j])-mx); sum+=e; o[j]=f2bf(e); }
      *(u16x8*)(prow + c8*8) = o;
    }
    #pragma unroll
    for(int j=80;j<96;j++) prow[j]=0;
    invr[tid] = 1.f/sum;
  }
  __syncthreads();
  for(int nh=0;nh<2;nh++){
    f32x4 Oa[2][8]={};
    for(int kt2=0;kt2<3;kt2++){
      for(int j=0;j<2;j++){
        int chunk=tid+j*256;
        int co=chunk>>2, ko2=(chunk&3)*8;
        g2l16(vT + ((size_t)(b*256+nh*128+co)*96 + kt2*32+ko2), &KVs[(size_t)chunk*8]);
      }
      __syncthreads();
      bf16x8 af[2], bfv[8];
      for(int mf=0;mf<2;mf++) af[mf]=ldfrag(&Pb[(w*32+mf*16+ln)*104 + kt2*32+qd*8]);
      for(int nf=0;nf<8;nf++) bfv[nf]=ldfrag(&KVs[(nf*16+ln)*32+qd*8]);
      for(int mf=0;mf<2;mf++) for(int nf=0;nf<8;nf++)
        Oa[mf][nf]=__builtin_amdgcn_mfma_f32_16x16x32_bf16(af[mf],bfv[nf],Oa[mf][nf],0,0,0);
      __syncthreads();
    }
    for(int mf=0;mf<2;mf++){
      #pragma unroll
      for(int r=0;r<4;r++){
        int ml=w*32+mf*16+qd*4+r;
        float inv = invr[ml];
        for(int nf=0;nf<8;nf++){
          int nl=nh*128+nf*16+ln;
          ob[((size_t)(b*HW_+p0+ml))*256+nl]=f2bf(Oa[mf][nf][r]*inv);
        }
      }
    }
  }
}

// ---------------- K8: out = x + (wo @ o^T) + bo, written NCHW ----------------
__global__ __launch_bounds__(256) void k_oproj(const u16* __restrict__ ob, const u16* __restrict__ woB,
    const float* __restrict__ bo, const float* __restrict__ x, float* __restrict__ outp){
  __shared__ u16 As[128*32];
  __shared__ u16 Bs[128*32];
  int bid=blockIdx.x;
  int b=bid>>6; int rr=bid&63; int cm=rr>>5, pt=rr&31;
  int c0=cm*128, p0=pt*128;
  int tid=threadIdx.x, w=tid>>6, lane=tid&63, ln=lane&15, qd=lane>>4, wm=w>>1, wn=w&1;
  int srow=tid>>2, koff=(tid&3)*8;
  f32x4 acc[4][4]={};
  for(int kt=0;kt<8;kt++){
    for(int j=0;j<2;j++){
      int m=srow+j*64;
      g2l16(woB + ((size_t)(c0+m)*256 + kt*32+koff),        &As[(size_t)tid*8+j*2048]);
      g2l16(ob  + ((size_t)(b*HW_+p0+m)*256 + kt*32+koff),  &Bs[(size_t)tid*8+j*2048]);
    }
    __syncthreads();
    bf16x8 af[4], bfv[4];
    for(int mf=0;mf<4;mf++) af[mf]=ldfrag(&As[(wm*64+mf*16+ln)*32+qd*8]);
    for(int nf=0;nf<4;nf++) bfv[nf]=ldfrag(&Bs[(wn*64+nf*16+ln)*32+qd*8]);
    for(int mf=0;mf<4;mf++) for(int nf=0;nf<4;nf++)
      acc[mf][nf]=__builtin_amdgcn_mfma_f32_16x16x32_bf16(af[mf],bfv[nf],acc[mf][nf],0,0,0);
    __syncthreads();
  }
  for(int mf=0;mf<4;mf++) for(int r=0;r<4;r++){
    int cl=c0+wm*64+mf*16+qd*4+r;
    float bias=bo[cl];
    for(int nf=0;nf<4;nf++){
      int pl=p0+wn*64+nf*16+ln;
      size_t idx=((size_t)(b*C_+cl))*HW_+pl;
      outp[idx]=x[idx]+acc[mf][nf][r]+bias;
    }
  }
}

extern "C" void kernel_launch(void* const* d_in, const int* in_sizes, int n_in,
                              void* d_out, int out_size, void* d_ws, size_t ws_size,
                              hipStream_t stream){
  const float* x      = (const float*)d_in[0];
  const float* ctx    = (const float*)d_in[1];
  const float* conv_w = (const float*)d_in[2];
  const float* conv_b = (const float*)d_in[3];
  const float* gnw    = (const float*)d_in[4];
  const float* gnb    = (const float*)d_in[5];
  const float* wq     = (const float*)d_in[6];
  const float* bq     = (const float*)d_in[7];
  const float* wk     = (const float*)d_in[8];
  const float* bk     = (const float*)d_in[9];
  const float* wv     = (const float*)d_in[10];
  const float* bv     = (const float*)d_in[11];
  const float* wo     = (const float*)d_in[12];
  const float* bo     = (const float*)d_in[13];
  char* ws = (char*)d_ws;
  u16* xpT  = (u16*)(ws + 0);            // 35,684,352 ; reused as q after conv
  u16* wBt  = (u16*)(ws + 35684352);     //  1,179,648
  u16* wqB  = (u16*)(ws + 36864000);     //    131,072
  u16* wkvB = (u16*)(ws + 36995072);     //    786,432
  u16* woB  = (u16*)(ws + 37781504);     //    131,072
  u16* ctxB = (u16*)(ws + 37912576);     //  1,892,352 (+74KB OOB read slack into hbuf)
  u16* hbuf = (u16*)(ws + 39804928);     // 33,554,432 (raw conv output)
  u16* kbv  = (u16*)(ws + 73359360);     //    630,784
  u16* vT   = (u16*)(ws + 73990144);     //    786,432
  u16* obuf = (u16*)(ws + 74776576);     // 33,554,432
  float* stats = (float*)(ws + 108331008); // 2048
  u16* qb = xpT;
  float* outp = (float*)d_out;

  k_prep  <<<9106, 256, 0, stream>>>(x, xpT, conv_w, wq, wo, wk, wv, ctx, wBt, wqB, woB, wkvB, ctxB, stats);
  k_conv  <<<512,  256, 0, stream>>>(xpT, wBt, conv_b, hbuf, stats);
  k_qgn   <<<512,  256, 0, stream>>>(hbuf, wqB, stats, gnw, gnb, bq, qb);
  k_kvproj<<<160,  256, 0, stream>>>(ctxB, wkvB, bk, bv, kbv, vT);
  k_attn  <<<512,  256, 0, stream>>>(qb, kbv, vT, obuf);
  k_oproj <<<1024, 256, 0, stream>>>(obuf, woB, bo, x, outp);
}

// Round 4
// 397.467 us; speedup vs baseline: 1.0693x; 1.0693x over previous
//
#include <hip/hip_runtime.h>
#include <stdint.h>

#define B_  16
#define C_  256
#define HW_ 4096
#define Hp  66
#define PP  4356   // 66*66
#define EPS_ 1e-5f

typedef unsigned short u16;
typedef unsigned int   u32;
typedef __attribute__((ext_vector_type(4))) float  f32x4;
typedef __attribute__((ext_vector_type(8))) __bf16 bf16x8;
typedef __attribute__((ext_vector_type(8))) u16    u16x8;

__device__ __forceinline__ float bf2f(u16 u){ u32 x = ((u32)u)<<16; float f; __builtin_memcpy(&f,&x,4); return f; }
__device__ __forceinline__ u16 f2bf(float f){ u32 x; __builtin_memcpy(&x,&f,4); u32 r = x + 0x7fffu + ((x>>16)&1u); return (u16)(r>>16); }

__device__ __forceinline__ void g2l16(const void* g, void* l){
  __builtin_amdgcn_global_load_lds((__attribute__((address_space(1))) void*)(void*)g,
                                   (__attribute__((address_space(3))) void*)l, 16, 0, 0);
}
__device__ __forceinline__ bf16x8 ldfrag(const u16* p){
  u16x8 r = *(const u16x8*)p;
  return __builtin_bit_cast(bf16x8, r);
}

// ---------------- K0: pad+transpose x AND repack weights (merged, block-range split) -----
// Layouts:
//   xpT: [b][ci(8)][atom(4)][PP pixels][8ch]
//   wBt: [ci(8)][tap(9)][atom(4)][co(256)][8ch]
__global__ __launch_bounds__(256) void k_prep(const float* __restrict__ x, u16* __restrict__ xpT,
    const float* __restrict__ conv_w, const float* __restrict__ wq, const float* __restrict__ wo,
    const float* __restrict__ wk, const float* __restrict__ wv, const float* __restrict__ ctx,
    u16* __restrict__ wBt, u16* __restrict__ wqB, u16* __restrict__ woB,
    u16* __restrict__ wkvB, u16* __restrict__ ctxB, float* __restrict__ stats){
  __shared__ float Lt[64*65];
  int bid = blockIdx.x; int tid = threadIdx.x;
  if(bid >= 1056){
    int i = (bid-1056)*256 + tid;
    if(i < 589824){
      int j = i&7, co = (i>>3)&255, atom = (i>>11)&3, g = i>>13;   // g in [0,72)
      int t = g%9, cic = g/9;
      int ciF = cic*32 + atom*8 + j;
      wBt[i] = f2bf(conv_w[(co*256+ciF)*9 + t]); return;
    }
    i -= 589824;
    if(i < 65536){ wqB[i] = f2bf(wq[i]); return; } i -= 65536;
    if(i < 65536){ woB[i] = f2bf(wo[i]); return; } i -= 65536;
    if(i < 196608){ wkvB[i] = f2bf(wk[i]); return; } i -= 196608;
    if(i < 196608){ wkvB[196608+i] = f2bf(wv[i]); return; } i -= 196608;
    if(i < 946176){ ctxB[i] = f2bf(ctx[i]); return; } i -= 946176;
    if(i < 512){ stats[i] = 0.f; }
    return;
  }
  int b = bid/66, hh = bid - b*66;
  if(hh==0 || hh==65){
    for(int i=tid;i<32*264;i+=256){
      int pl = i/264, off = i - pl*264;
      u32* p = (u32*)(xpT + ((size_t)(b*32+pl)*PP + (size_t)hh*Hp)*8);
      p[off] = 0u;
    }
    return;
  }
  {
    int pl = tid>>3, q = tid&7;
    size_t base = ((size_t)(b*32+pl)*PP + (size_t)hh*Hp + (q>=4?65:0))*8;
    ((u32*)(xpT + base))[q&3] = 0u;
  }
  int h = hh-1;
  for(int cc=0; cc<4; cc++){
    int c0=cc*64;
    int ci = tid>>2, w0 = (tid&3)*16;
    const float* xs = x + ((size_t)(b*C_ + c0+ci)*HW_) + h*64 + w0;
    for(int j=0;j<4;j++){
      float4 v = *(const float4*)(xs + j*4);
      Lt[ci*65 + w0 + j*4 + 0] = v.x;
      Lt[ci*65 + w0 + j*4 + 1] = v.y;
      Lt[ci*65 + w0 + j*4 + 2] = v.z;
      Lt[ci*65 + w0 + j*4 + 3] = v.w;
    }
    __syncthreads();
    int w = tid>>2, cj = (tid&3)*16;
    union { u16 u[16]; uint4 v[2]; } outu;
    for(int j=0;j<16;j++) outu.u[j] = f2bf(Lt[(cj+j)*65 + w]);
    int chan = c0 + cj;
    int cic = chan>>5, at0 = (chan>>3)&3;
    u16* dst = xpT + (((size_t)(b*8+cic)*4 + at0)*PP + (size_t)hh*Hp + w + 1)*8;
    *(uint4*)dst = outu.v[0];
    *(uint4*)(dst + (size_t)PP*8) = outu.v[1];
    __syncthreads();
  }
}

// ---------------- K2: conv implicit GEMM, B-weights direct global->register ----------------
// LDS-BW analysis: staging B through LDS made every wave read 12KB/step from LDS
// (85 B/cyc/CU ceiling -> ~1100 cyc/step, MfmaUtil capped at ~25%). Now B-frags are
// per-lane global_load_dwordx4 (L1-served across the 4 waves sharing wn); LDS holds A
// only (4KB/wave/step). M=256px per block (512 thr, 8 waves, grid=256 = 1 block/CU)
// halves B L2 traffic. Tap loop is barrier-free; one __syncthreads per ci for A dbuf.
__global__ __launch_bounds__(512, 2) void k_conv(const u16* __restrict__ xpT, const u16* __restrict__ wBt,
    const float* __restrict__ conv_b, u16* __restrict__ h, float* __restrict__ stats){
  __shared__ u16 As[2][4*396*8];   // [buf][atom(4)][396 px][8ch] = 25,344 B each
  int bid = blockIdx.x;
  int b = bid >> 4, hp = bid & 15;
  int tid = threadIdx.x;
  int w = tid>>6, lane = tid&63, ln = lane&15, qd = lane>>4;
  int wm = w&3, wn = w>>2;
  f32x4 acc[4][8] = {};
  int hr_[4], wp_[4];
  #pragma unroll
  for(int mf=0;mf<4;mf++){ int p = wm*64 + mf*16 + ln; hr_[mf] = p>>6; wp_[mf] = p&63; }
  // per-lane B base: wBt[(g*4+qd)*2048 + (wn*128 + nf*16 + ln)*8]
  const u16* bbase = wBt + (size_t)qd*2048 + wn*1024 + ln*8;

  // prologue: stage A(ci=0); load B(g=0) to regs
  #pragma unroll
  for(int r=0;r<4;r++){
    int c = r*512 + tid;
    if(c < 1584){
      int atom = c/396, ipix = c - atom*396;
      g2l16(xpT + (((size_t)(b*8+0)*4 + atom)*PP + hp*264 + ipix)*8, &As[0][c*8]);
    }
  }
  bf16x8 bC[8], bN[8];
  #pragma unroll
  for(int nf=0;nf<8;nf++) bC[nf] = ldfrag(bbase + nf*128);
  __syncthreads();

  for(int ci=0; ci<8; ci++){
    int ab = ci&1;
    #pragma unroll
    for(int t=0;t<9;t++){
      int g = ci*9 + t;
      // prefetch next step's B frags into registers
      if(g < 71){
        #pragma unroll
        for(int nf=0;nf<8;nf++) bN[nf] = ldfrag(bbase + (size_t)(g+1)*8192 + nf*128);
      }
      // stage next ci's A slab (spread over taps 0..3), into the other buffer
      if(ci < 7 && t < 4){
        int c = t*512 + tid;
        if(c < 1584){
          int atom = c/396, ipix = c - atom*396;
          g2l16(xpT + (((size_t)(b*8+ci+1)*4 + atom)*PP + hp*264 + ipix)*8, &As[ab^1][c*8]);
        }
      }
      int dy = (t*11)>>5, dx = t - dy*3;
      bf16x8 af[4];
      #pragma unroll
      for(int mf=0;mf<4;mf++){
        int ipix = (hr_[mf]+dy)*66 + wp_[mf] + dx;
        af[mf] = ldfrag(&As[ab][((size_t)qd*396 + ipix)*8]);
      }
      #pragma unroll
      for(int mf=0;mf<4;mf++)
        #pragma unroll
        for(int nf=0;nf<8;nf++)
          acc[mf][nf] = __builtin_amdgcn_mfma_f32_16x16x32_bf16(af[mf], bC[nf], acc[mf][nf], 0,0,0);
      if(g < 71){
        #pragma unroll
        for(int nf=0;nf<8;nf++) bC[nf] = bN[nf];
      }
    }
    __syncthreads();   // A dbuf swap (drains the g2l16 stages; once per 9 taps)
  }

  float s[4]={0,0,0,0}, q[4]={0,0,0,0};
  int p0 = hp*256;
  for(int nf=0;nf<8;nf++){
    int n = wn*128 + nf*16 + ln;
    float bias = conv_b[n];
    for(int mf=0;mf<4;mf++){
      for(int r=0;r<4;r++){
        int p = wm*64 + mf*16 + qd*4 + r;
        float v = acc[mf][nf][r] + bias;
        h[((size_t)(b*HW_ + p0 + p))*C_ + n] = f2bf(v);
        s[nf>>1]+=v; q[nf>>1]+=v*v;
      }
    }
  }
  for(int off=32;off>=1;off>>=1){
    #pragma unroll
    for(int g=0;g<4;g++){ s[g]+=__shfl_down(s[g],off,64); q[g]+=__shfl_down(q[g],off,64); }
  }
  if(lane==0){
    #pragma unroll
    for(int g=0;g<4;g++){
      int gg = wn*4 + g;
      atomicAdd(&stats[(b*8 + gg)*2+0], s[g]);
      atomicAdd(&stats[(b*8 + gg)*2+1], q[g]);
    }
  }
}

// ---------------- K5: fused GN+SiLU+qproj: q = silu(gn(h)) @ wq^T + bq ----------------
__global__ __launch_bounds__(256, 2) void k_qgn(const u16* __restrict__ hbuf, const u16* __restrict__ wqB,
    const float* __restrict__ stats, const float* __restrict__ gnw, const float* __restrict__ gnb,
    const float* __restrict__ bq, u16* __restrict__ qb){
  __shared__ u16 As[128*32];
  __shared__ u16 Bs[256*32];
  int mt = blockIdx.x;
  int b = mt >> 5;
  int tid = threadIdx.x;
  int w = tid>>6, lane = tid&63, ln = lane&15, qd = lane>>4;
  int wm = w&1, wn = w>>1;
  int pr = tid>>1, half = tid&1;
  const u16* hsrc = hbuf + ((size_t)(mt*128+pr))*256 + half*16;
  f32x4 acc[4][8] = {};
  uint4 ra0, ra1, rb0, rb1;
  ra0 = *(const uint4*)(hsrc);
  ra1 = *(const uint4*)(hsrc + 8);
  for(int kt=0; kt<8; kt++){
    float sm = stats[(b*8+kt)*2], qm = stats[(b*8+kt)*2+1];
    float mean = sm*(1.f/131072.f);
    float rstd = rsqrtf(qm*(1.f/131072.f) - mean*mean + EPS_);
    int c0 = kt*32 + half*16;
    float4 gw0 = *(const float4*)(gnw+c0), gw1 = *(const float4*)(gnw+c0+4);
    float4 gw2 = *(const float4*)(gnw+c0+8), gw3 = *(const float4*)(gnw+c0+12);
    float4 gb0 = *(const float4*)(gnb+c0), gb1 = *(const float4*)(gnb+c0+4);
    float4 gb2 = *(const float4*)(gnb+c0+8), gb3 = *(const float4*)(gnb+c0+12);
    float gwv[16] = {gw0.x,gw0.y,gw0.z,gw0.w, gw1.x,gw1.y,gw1.z,gw1.w,
                     gw2.x,gw2.y,gw2.z,gw2.w, gw3.x,gw3.y,gw3.z,gw3.w};
    float gbv[16] = {gb0.x,gb0.y,gb0.z,gb0.w, gb1.x,gb1.y,gb1.z,gb1.w,
                     gb2.x,gb2.y,gb2.z,gb2.w, gb3.x,gb3.y,gb3.z,gb3.w};
    u16 inu[16];
    ((uint4*)inu)[0] = ra0; ((uint4*)inu)[1] = ra1;
    u16 outu[16];
    #pragma unroll
    for(int j=0;j<16;j++){
      float v = bf2f(inu[j]);
      v = (v-mean)*rstd*gwv[j] + gbv[j];
      float s = v/(1.f+__expf(-v));
      outu[j] = f2bf(s);
    }
    u16* adst = &As[pr*32 + half*16];
    ((uint4*)adst)[0] = ((uint4*)outu)[0];
    ((uint4*)adst)[1] = ((uint4*)outu)[1];
    #pragma unroll
    for(int r=0;r<4;r++){
      int c = r*256 + tid;
      int co = c>>2, atom = c&3;
      g2l16(wqB + (size_t)co*256 + kt*32 + atom*8, &Bs[c*8]);
    }
    if(kt<7){
      rb0 = *(const uint4*)(hsrc + (kt+1)*32);
      rb1 = *(const uint4*)(hsrc + (kt+1)*32 + 8);
    }
    __syncthreads();
    bf16x8 af[4], bfv[8];
    #pragma unroll
    for(int mf=0;mf<4;mf++) af[mf] = ldfrag(&As[(wm*64+mf*16+ln)*32 + qd*8]);
    #pragma unroll
    for(int nf=0;nf<8;nf++) bfv[nf] = ldfrag(&Bs[(wn*128+nf*16+ln)*32 + qd*8]);
    #pragma unroll
    for(int mf=0;mf<4;mf++)
      #pragma unroll
      for(int nf=0;nf<8;nf++)
        acc[mf][nf] = __builtin_amdgcn_mfma_f32_16x16x32_bf16(af[mf], bfv[nf], acc[mf][nf], 0,0,0);
    __syncthreads();
    ra0 = rb0; ra1 = rb1;
  }
  for(int nf=0;nf<8;nf++){
    int n = wn*128 + nf*16 + ln;
    float bias = bq[n];
    for(int mf=0;mf<4;mf++){
      for(int r=0;r<4;r++){
        int ml = wm*64 + mf*16 + qd*4 + r;
        qb[((size_t)(mt*128+ml))*256 + n] = f2bf(acc[mf][nf][r]+bias);
      }
    }
  }
}

// ---------------- K6: k,v = ctx @ {wk,wv}^T + b, 64x64 tiles, 160 blocks ----------------
__global__ __launch_bounds__(256) void k_kvproj(const u16* __restrict__ ctxB, const u16* __restrict__ wkvB,
    const float* __restrict__ bk, const float* __restrict__ bv,
    u16* __restrict__ kb, u16* __restrict__ vT){
  __shared__ u16 As[64*128];
  __shared__ u16 Bs[64*128];
  int bid = blockIdx.x;
  int nt = bid & 7, mt = bid >> 3;
  int n0 = nt*64, m0 = mt*64;
  int tid=threadIdx.x, w=tid>>6, lane=tid&63, ln=lane&15, qd=lane>>4;
  int wm = w&1, wn = w>>1;
  f32x4 acc[2][2]={};
  for(int kt=0;kt<6;kt++){
    #pragma unroll
    for(int r=0;r<4;r++){
      int c = r*256 + tid;
      int row = c>>4, atom = c&15;
      g2l16(ctxB + ((size_t)(m0+row)*768 + kt*128 + atom*8), &As[c*8]);
      g2l16(wkvB + ((size_t)(n0+row)*768 + kt*128 + atom*8), &Bs[c*8]);
    }
    __syncthreads();
    #pragma unroll
    for(int kk=0;kk<4;kk++){
      bf16x8 af[2], bfv[2];
      #pragma unroll
      for(int mf=0;mf<2;mf++) af[mf]=ldfrag(&As[(wm*32+mf*16+ln)*128 + kk*32 + qd*8]);
      #pragma unroll
      for(int nf=0;nf<2;nf++) bfv[nf]=ldfrag(&Bs[(wn*32+nf*16+ln)*128 + kk*32 + qd*8]);
      #pragma unroll
      for(int mf=0;mf<2;mf++)
        #pragma unroll
        for(int nf=0;nf<2;nf++)
          acc[mf][nf]=__builtin_amdgcn_mfma_f32_16x16x32_bf16(af[mf],bfv[nf],acc[mf][nf],0,0,0);
    }
    __syncthreads();
  }
  for(int mf=0;mf<2;mf++) for(int nf=0;nf<2;nf++){
    int ng = n0 + wn*32 + nf*16 + ln;
    float bias = ng<256 ? bk[ng] : bv[ng-256];
    for(int r=0;r<4;r++){
      int mg = m0 + wm*32 + mf*16 + qd*4 + r;
      if(mg<1232){
        float v=acc[mf][nf][r]+bias;
        int bb=mg/77, l=mg-bb*77;
        if(ng<256) kb[((size_t)(bb*77+l))*256+ng]=f2bf(v);
        else vT[((size_t)(bb*256+(ng-256)))*96 + l]=f2bf(v);
      }
    }
  }
}

// ---------------- K7: attention per (b, 128-pixel q tile) ----------------
__global__ __launch_bounds__(256) void k_attn(const u16* __restrict__ qg, const u16* __restrict__ kb,
    const u16* __restrict__ vT, u16* __restrict__ ob){
  __shared__ u16 Qs[4096];        // 128 x 32
  __shared__ u16 KVs[4096];       // up to 128 x 32
  __shared__ u16 Sb[128*88];      // S scores, bf16, 88-stride
  __shared__ u16 Pb[128*104];     // P (unnormalized), bf16, k-padded to 96 (+8)
  __shared__ float invr[128];
  int bid=blockIdx.x; int b=bid>>5, qt=bid&31; int p0=qt*128;
  int tid=threadIdx.x, w=tid>>6, lane=tid&63, ln=lane&15, qd=lane>>4;
  int srow=tid>>2, koff=(tid&3)*8;
  f32x4 Sa[2][5]={};
  for(int kt=0;kt<8;kt++){
    for(int j=0;j<2;j++){
      int m=srow+j*64;
      g2l16(qg + ((size_t)(b*HW_+p0+m)*256 + kt*32+koff), &Qs[(size_t)tid*8+j*2048]);
    }
    for(int j=0;j<2;j++){
      int cja = tid + j*256;
      if(cja < 320){
        int l = cja>>2, ko2=(cja&3)*8;
        g2l16(kb + ((size_t)(b*77+l)*256 + kt*32+ko2), &KVs[(size_t)cja*8]);
      }
    }
    __syncthreads();
    bf16x8 af[2], bfv[5];
    for(int mf=0;mf<2;mf++) af[mf]=ldfrag(&Qs[(w*32+mf*16+ln)*32+qd*8]);
    for(int nf=0;nf<5;nf++) bfv[nf]=ldfrag(&KVs[(nf*16+ln)*32+qd*8]);
    for(int mf=0;mf<2;mf++) for(int nf=0;nf<5;nf++)
      Sa[mf][nf]=__builtin_amdgcn_mfma_f32_16x16x32_bf16(af[mf],bfv[nf],Sa[mf][nf],0,0,0);
    __syncthreads();
  }
  for(int mf=0;mf<2;mf++) for(int nf=0;nf<5;nf++) for(int r=0;r<4;r++){
    int ml=w*32+mf*16+qd*4+r, nl=nf*16+ln;
    Sb[ml*88+nl]=f2bf(Sa[mf][nf][r]*0.0625f);
  }
  __syncthreads();
  if(tid<128){
    u16* srp = &Sb[tid*88];
    srp[77]=0xFF80u; srp[78]=0xFF80u; srp[79]=0xFF80u;   // -inf tail pad
    float mx=-1e30f;
    #pragma unroll
    for(int c8=0;c8<10;c8++){
      u16x8 v = *(const u16x8*)(srp + c8*8);
      #pragma unroll
      for(int j=0;j<8;j++) mx = fmaxf(mx, bf2f(v[j]));
    }
    u16* prow = &Pb[tid*104];
    float sum=0.f;
    #pragma unroll
    for(int c8=0;c8<10;c8++){
      u16x8 v = *(const u16x8*)(srp + c8*8);
      u16x8 o;
      #pragma unroll
      for(int j=0;j<8;j++){ float e=__expf(bf2f(v[j])-mx); sum+=e; o[j]=f2bf(e); }
      *(u16x8*)(prow + c8*8) = o;
    }
    #pragma unroll
    for(int j=80;j<96;j++) prow[j]=0;
    invr[tid] = 1.f/sum;
  }
  __syncthreads();
  for(int nh=0;nh<2;nh++){
    f32x4 Oa[2][8]={};
    for(int kt2=0;kt2<3;kt2++){
      for(int j=0;j<2;j++){
        int chunk=tid+j*256;
        int co=chunk>>2, ko2=(chunk&3)*8;
        g2l16(vT + ((size_t)(b*256+nh*128+co)*96 + kt2*32+ko2), &KVs[(size_t)chunk*8]);
      }
      __syncthreads();
      bf16x8 af[2], bfv[8];
      for(int mf=0;mf<2;mf++) af[mf]=ldfrag(&Pb[(w*32+mf*16+ln)*104 + kt2*32+qd*8]);
      for(int nf=0;nf<8;nf++) bfv[nf]=ldfrag(&KVs[(nf*16+ln)*32+qd*8]);
      for(int mf=0;mf<2;mf++) for(int nf=0;nf<8;nf++)
        Oa[mf][nf]=__builtin_amdgcn_mfma_f32_16x16x32_bf16(af[mf],bfv[nf],Oa[mf][nf],0,0,0);
      __syncthreads();
    }
    for(int mf=0;mf<2;mf++){
      #pragma unroll
      for(int r=0;r<4;r++){
        int ml=w*32+mf*16+qd*4+r;
        float inv = invr[ml];
        for(int nf=0;nf<8;nf++){
          int nl=nh*128+nf*16+ln;
          ob[((size_t)(b*HW_+p0+ml))*256+nl]=f2bf(Oa[mf][nf][r]*inv);
        }
      }
    }
  }
}

// ---------------- K8: out = x + (wo @ o^T) + bo, written NCHW ----------------
__global__ __launch_bounds__(256) void k_oproj(const u16* __restrict__ ob, const u16* __restrict__ woB,
    const float* __restrict__ bo, const float* __restrict__ x, float* __restrict__ outp){
  __shared__ u16 As[128*32];
  __shared__ u16 Bs[128*32];
  int bid=blockIdx.x;
  int b=bid>>6; int rr=bid&63; int cm=rr>>5, pt=rr&31;
  int c0=cm*128, p0=pt*128;
  int tid=threadIdx.x, w=tid>>6, lane=tid&63, ln=lane&15, qd=lane>>4, wm=w>>1, wn=w&1;
  int srow=tid>>2, koff=(tid&3)*8;
  f32x4 acc[4][4]={};
  for(int kt=0;kt<8;kt++){
    for(int j=0;j<2;j++){
      int m=srow+j*64;
      g2l16(woB + ((size_t)(c0+m)*256 + kt*32+koff),        &As[(size_t)tid*8+j*2048]);
      g2l16(ob  + ((size_t)(b*HW_+p0+m)*256 + kt*32+koff),  &Bs[(size_t)tid*8+j*2048]);
    }
    __syncthreads();
    bf16x8 af[4], bfv[4];
    for(int mf=0;mf<4;mf++) af[mf]=ldfrag(&As[(wm*64+mf*16+ln)*32+qd*8]);
    for(int nf=0;nf<4;nf++) bfv[nf]=ldfrag(&Bs[(wn*64+nf*16+ln)*32+qd*8]);
    for(int mf=0;mf<4;mf++) for(int nf=0;nf<4;nf++)
      acc[mf][nf]=__builtin_amdgcn_mfma_f32_16x16x32_bf16(af[mf],bfv[nf],acc[mf][nf],0,0,0);
    __syncthreads();
  }
  for(int mf=0;mf<4;mf++) for(int r=0;r<4;r++){
    int cl=c0+wm*64+mf*16+qd*4+r;
    float bias=bo[cl];
    for(int nf=0;nf<4;nf++){
      int pl=p0+wn*64+nf*16+ln;
      size_t idx=((size_t)(b*C_+cl))*HW_+pl;
      outp[idx]=x[idx]+acc[mf][nf][r]+bias;
    }
  }
}

extern "C" void kernel_launch(void* const* d_in, const int* in_sizes, int n_in,
                              void* d_out, int out_size, void* d_ws, size_t ws_size,
                              hipStream_t stream){
  const float* x      = (const float*)d_in[0];
  const float* ctx    = (const float*)d_in[1];
  const float* conv_w = (const float*)d_in[2];
  const float* conv_b = (const float*)d_in[3];
  const float* gnw    = (const float*)d_in[4];
  const float* gnb    = (const float*)d_in[5];
  const float* wq     = (const float*)d_in[6];
  const float* bq     = (const float*)d_in[7];
  const float* wk     = (const float*)d_in[8];
  const float* bk     = (const float*)d_in[9];
  const float* wv     = (const float*)d_in[10];
  const float* bv     = (const float*)d_in[11];
  const float* wo     = (const float*)d_in[12];
  const float* bo     = (const float*)d_in[13];
  char* ws = (char*)d_ws;
  u16* xpT  = (u16*)(ws + 0);            // 35,684,352 ; reused as q after conv
  u16* wBt  = (u16*)(ws + 35684352);     //  1,179,648
  u16* wqB  = (u16*)(ws + 36864000);     //    131,072
  u16* wkvB = (u16*)(ws + 36995072);     //    786,432
  u16* woB  = (u16*)(ws + 37781504);     //    131,072
  u16* ctxB = (u16*)(ws + 37912576);     //  1,892,352 (+74KB OOB read slack into hbuf)
  u16* hbuf = (u16*)(ws + 39804928);     // 33,554,432 (raw conv output)
  u16* kbv  = (u16*)(ws + 73359360);     //    630,784
  u16* vT   = (u16*)(ws + 73990144);     //    786,432
  u16* obuf = (u16*)(ws + 74776576);     // 33,554,432
  float* stats = (float*)(ws + 108331008); // 2048
  u16* qb = xpT;
  float* outp = (float*)d_out;

  k_prep  <<<9106, 256, 0, stream>>>(x, xpT, conv_w, wq, wo, wk, wv, ctx, wBt, wqB, woB, wkvB, ctxB, stats);
  k_conv  <<<256,  512, 0, stream>>>(xpT, wBt, conv_b, hbuf, stats);
  k_qgn   <<<512,  256, 0, stream>>>(hbuf, wqB, stats, gnw, gnb, bq, qb);
  k_kvproj<<<160,  256, 0, stream>>>(ctxB, wkvB, bk, bv, kbv, vT);
  k_attn  <<<512,  256, 0, stream>>>(qb, kbv, vT, obuf);
  k_oproj <<<1024, 256, 0, stream>>>(obuf, woB, bo, x, outp);
}

// Round 5
// 366.330 us; speedup vs baseline: 1.1602x; 1.0850x over previous
//
#include <hip/hip_runtime.h>
#include <stdint.h>

#define B_  16
#define C_  256
#define HW_ 4096
#define Hp  66
#define PP  4356   // 66*66
#define EPS_ 1e-5f

typedef unsigned short u16;
typedef unsigned int   u32;
typedef __attribute__((ext_vector_type(4))) float  f32x4;
typedef __attribute__((ext_vector_type(8))) __bf16 bf16x8;
typedef __attribute__((ext_vector_type(8))) u16    u16x8;

__device__ __forceinline__ float bf2f(u16 u){ u32 x = ((u32)u)<<16; float f; __builtin_memcpy(&f,&x,4); return f; }
__device__ __forceinline__ u16 f2bf(float f){ u32 x; __builtin_memcpy(&x,&f,4); u32 r = x + 0x7fffu + ((x>>16)&1u); return (u16)(r>>16); }

__device__ __forceinline__ void g2l16(const void* g, void* l){
  __builtin_amdgcn_global_load_lds((__attribute__((address_space(1))) void*)(void*)g,
                                   (__attribute__((address_space(3))) void*)l, 16, 0, 0);
}
__device__ __forceinline__ bf16x8 ldfrag(const u16* p){
  u16x8 r = *(const u16x8*)p;
  return __builtin_bit_cast(bf16x8, r);
}

// ---------------- K0: pad+transpose x AND repack weights (merged, block-range split) -----
// Layouts (conflict-free atom-major LDS staging for k_conv):
//   xpT: [b][ci(8)][atom(4)][PP pixels][8ch]
//   wBt: [ci(8)][tap(9)][atom(4)][co(256)][8ch]
__global__ __launch_bounds__(256) void k_prep(const float* __restrict__ x, u16* __restrict__ xpT,
    const float* __restrict__ conv_w, const float* __restrict__ wq, const float* __restrict__ wo,
    const float* __restrict__ wk, const float* __restrict__ wv, const float* __restrict__ ctx,
    u16* __restrict__ wBt, u16* __restrict__ wqB, u16* __restrict__ woB,
    u16* __restrict__ wkvB, u16* __restrict__ ctxB, float* __restrict__ stats){
  __shared__ float Lt[64*65];
  int bid = blockIdx.x; int tid = threadIdx.x;
  if(bid >= 1056){
    int i = (bid-1056)*256 + tid;
    if(i < 589824){
      int j = i&7, co = (i>>3)&255, atom = (i>>11)&3, g = i>>13;   // g in [0,72)
      int t = g%9, cic = g/9;
      int ciF = cic*32 + atom*8 + j;
      wBt[i] = f2bf(conv_w[(co*256+ciF)*9 + t]); return;
    }
    i -= 589824;
    if(i < 65536){ wqB[i] = f2bf(wq[i]); return; } i -= 65536;
    if(i < 65536){ woB[i] = f2bf(wo[i]); return; } i -= 65536;
    if(i < 196608){ wkvB[i] = f2bf(wk[i]); return; } i -= 196608;
    if(i < 196608){ wkvB[196608+i] = f2bf(wv[i]); return; } i -= 196608;
    if(i < 946176){ ctxB[i] = f2bf(ctx[i]); return; } i -= 946176;
    if(i < 512){ stats[i] = 0.f; }
    return;
  }
  int b = bid/66, hh = bid - b*66;
  if(hh==0 || hh==65){
    for(int i=tid;i<32*264;i+=256){
      int pl = i/264, off = i - pl*264;
      u32* p = (u32*)(xpT + ((size_t)(b*32+pl)*PP + (size_t)hh*Hp)*8);
      p[off] = 0u;
    }
    return;
  }
  {
    int pl = tid>>3, q = tid&7;
    size_t base = ((size_t)(b*32+pl)*PP + (size_t)hh*Hp + (q>=4?65:0))*8;
    ((u32*)(xpT + base))[q&3] = 0u;
  }
  int h = hh-1;
  for(int cc=0; cc<4; cc++){
    int c0=cc*64;
    int ci = tid>>2, w0 = (tid&3)*16;
    const float* xs = x + ((size_t)(b*C_ + c0+ci)*HW_) + h*64 + w0;
    for(int j=0;j<4;j++){
      float4 v = *(const float4*)(xs + j*4);
      Lt[ci*65 + w0 + j*4 + 0] = v.x;
      Lt[ci*65 + w0 + j*4 + 1] = v.y;
      Lt[ci*65 + w0 + j*4 + 2] = v.z;
      Lt[ci*65 + w0 + j*4 + 3] = v.w;
    }
    __syncthreads();
    int w = tid>>2, cj = (tid&3)*16;
    union { u16 u[16]; uint4 v[2]; } outu;
    for(int j=0;j<16;j++) outu.u[j] = f2bf(Lt[(cj+j)*65 + w]);
    int chan = c0 + cj;
    int cic = chan>>5, at0 = (chan>>3)&3;
    u16* dst = xpT + (((size_t)(b*8+cic)*4 + at0)*PP + (size_t)hh*Hp + w + 1)*8;
    *(uint4*)dst = outu.v[0];
    *(uint4*)(dst + (size_t)PP*8) = outu.v[1];
    __syncthreads();
  }
}

// ---------------- K2: conv implicit GEMM (best measured variant: R2, 122.7us) ----------------
__global__ __launch_bounds__(256, 3) void k_conv(const u16* __restrict__ xpT, const u16* __restrict__ wBt,
    const float* __restrict__ conv_b, u16* __restrict__ h, float* __restrict__ stats){
  __shared__ u16 As[2][264*32];   // 33,792 B
  __shared__ u16 Bs[2][128*32];   // 16,384 B
  int bid0 = blockIdx.x;
  int l = (bid0 & 7)*128 + (bid0 >> 3);    // chunked XCD swizzle, 1024 % 8 == 0 (bijective)
  int b = l >> 6, hp = (l >> 1) & 31, nh = l & 1;
  int tid = threadIdx.x;
  int w = tid>>6, lane = tid&63, ln = lane&15, qd = lane>>4;
  int wm = w&1, wn = w>>1;
  f32x4 acc[4][4] = {};
  int hr_[4], wp_[4];
  #pragma unroll
  for(int mf=0;mf<4;mf++){ int p = wm*64 + mf*16 + ln; hr_[mf] = p>>6; wp_[mf] = p&63; }

  #pragma unroll
  for(int r=0;r<5;r++){
    int c = r*256 + tid;
    if(c < 1056){
      int atom = c/264, ipix = c - atom*264;
      g2l16(xpT + (((size_t)(b*8+0)*4 + atom)*PP + hp*132 + ipix)*8, &As[0][c*8]);
    }
  }
  #pragma unroll
  for(int r=0;r<2;r++){
    int c = r*256 + tid;
    int atom = c>>7, col = c&127;
    g2l16(wBt + ((size_t)atom*2048 + (nh*128+col)*8), &Bs[0][c*8]);
  }
  __syncthreads();

  int cb = 0;
  for(int ci=0; ci<8; ci++){
    int ca = ci&1;
    for(int t=0;t<9;t++){
      int tn = t+1, cin = ci;
      if(tn==9){ tn=0; cin=ci+1; }
      if(cin < 8){
        #pragma unroll
        for(int r=0;r<2;r++){
          int c = r*256 + tid;
          int atom = c>>7, col = c&127;
          g2l16(wBt + (((size_t)(cin*9+tn)*4 + atom)*2048 + (nh*128+col)*8), &Bs[cb^1][c*8]);
        }
      }
      if(t<5 && ci<7){
        int c = t*256 + tid;
        if(c < 1056){
          int atom = c/264, ipix = c - atom*264;
          g2l16(xpT + (((size_t)(b*8+ci+1)*4 + atom)*PP + hp*132 + ipix)*8, &As[ca^1][c*8]);
        }
      }
      int dy = (t*11)>>5, dx = t - dy*3;
      bf16x8 af[4], bfv[4];
      #pragma unroll
      for(int mf=0;mf<4;mf++){
        int ipix = (hr_[mf]+dy)*66 + wp_[mf] + dx;
        af[mf] = ldfrag(&As[ca][(qd*264 + ipix)*8]);
      }
      #pragma unroll
      for(int nf=0;nf<4;nf++) bfv[nf] = ldfrag(&Bs[cb][(qd*128 + wn*64+nf*16+ln)*8]);
      #pragma unroll
      for(int mf=0;mf<4;mf++)
        #pragma unroll
        for(int nf=0;nf<4;nf++)
          acc[mf][nf] = __builtin_amdgcn_mfma_f32_16x16x32_bf16(af[mf], bfv[nf], acc[mf][nf], 0,0,0);
      __syncthreads();
      cb ^= 1;
    }
  }
  float s[2]={0,0}, q[2]={0,0};
  int p0 = hp*128;
  for(int nf=0;nf<4;nf++){
    int n = nh*128 + wn*64 + nf*16 + ln;
    float bias = conv_b[n];
    for(int mf=0;mf<4;mf++){
      for(int r=0;r<4;r++){
        int p = wm*64 + mf*16 + qd*4 + r;
        float v = acc[mf][nf][r] + bias;
        h[((size_t)(b*HW_ + p0 + p))*C_ + n] = f2bf(v);
        s[nf>>1]+=v; q[nf>>1]+=v*v;
      }
    }
  }
  for(int off=32;off>=1;off>>=1){
    #pragma unroll
    for(int g=0;g<2;g++){ s[g]+=__shfl_down(s[g],off,64); q[g]+=__shfl_down(q[g],off,64); }
  }
  if(lane==0){
    #pragma unroll
    for(int g=0;g<2;g++){
      int gg = nh*4 + wn*2 + g;
      atomicAdd(&stats[(b*8 + gg)*2+0], s[g]);
      atomicAdd(&stats[(b*8 + gg)*2+1], q[g]);
    }
  }
}

// ---------------- K5: fused GN+SiLU+qproj: q = silu(gn(h)) @ wq^T + bq ----------------
__global__ __launch_bounds__(256, 2) void k_qgn(const u16* __restrict__ hbuf, const u16* __restrict__ wqB,
    const float* __restrict__ stats, const float* __restrict__ gnw, const float* __restrict__ gnb,
    const float* __restrict__ bq, u16* __restrict__ qb){
  __shared__ u16 As[128*32];
  __shared__ u16 Bs[256*32];
  int mt = blockIdx.x;
  int b = mt >> 5;
  int tid = threadIdx.x;
  int w = tid>>6, lane = tid&63, ln = lane&15, qd = lane>>4;
  int wm = w&1, wn = w>>1;
  int pr = tid>>1, half = tid&1;
  const u16* hsrc = hbuf + ((size_t)(mt*128+pr))*256 + half*16;
  f32x4 acc[4][8] = {};
  uint4 ra0, ra1, rb0, rb1;
  ra0 = *(const uint4*)(hsrc);
  ra1 = *(const uint4*)(hsrc + 8);
  for(int kt=0; kt<8; kt++){
    float sm = stats[(b*8+kt)*2], qm = stats[(b*8+kt)*2+1];
    float mean = sm*(1.f/131072.f);
    float rstd = rsqrtf(qm*(1.f/131072.f) - mean*mean + EPS_);
    int c0 = kt*32 + half*16;
    float4 gw0 = *(const float4*)(gnw+c0), gw1 = *(const float4*)(gnw+c0+4);
    float4 gw2 = *(const float4*)(gnw+c0+8), gw3 = *(const float4*)(gnw+c0+12);
    float4 gb0 = *(const float4*)(gnb+c0), gb1 = *(const float4*)(gnb+c0+4);
    float4 gb2 = *(const float4*)(gnb+c0+8), gb3 = *(const float4*)(gnb+c0+12);
    float gwv[16] = {gw0.x,gw0.y,gw0.z,gw0.w, gw1.x,gw1.y,gw1.z,gw1.w,
                     gw2.x,gw2.y,gw2.z,gw2.w, gw3.x,gw3.y,gw3.z,gw3.w};
    float gbv[16] = {gb0.x,gb0.y,gb0.z,gb0.w, gb1.x,gb1.y,gb1.z,gb1.w,
                     gb2.x,gb2.y,gb2.z,gb2.w, gb3.x,gb3.y,gb3.z,gb3.w};
    u16 inu[16];
    ((uint4*)inu)[0] = ra0; ((uint4*)inu)[1] = ra1;
    u16 outu[16];
    #pragma unroll
    for(int j=0;j<16;j++){
      float v = bf2f(inu[j]);
      v = (v-mean)*rstd*gwv[j] + gbv[j];
      float s = v/(1.f+__expf(-v));
      outu[j] = f2bf(s);
    }
    u16* adst = &As[pr*32 + half*16];
    ((uint4*)adst)[0] = ((uint4*)outu)[0];
    ((uint4*)adst)[1] = ((uint4*)outu)[1];
    #pragma unroll
    for(int r=0;r<4;r++){
      int c = r*256 + tid;
      int co = c>>2, atom = c&3;
      g2l16(wqB + (size_t)co*256 + kt*32 + atom*8, &Bs[c*8]);
    }
    if(kt<7){
      rb0 = *(const uint4*)(hsrc + (kt+1)*32);
      rb1 = *(const uint4*)(hsrc + (kt+1)*32 + 8);
    }
    __syncthreads();
    bf16x8 af[4], bfv[8];
    #pragma unroll
    for(int mf=0;mf<4;mf++) af[mf] = ldfrag(&As[(wm*64+mf*16+ln)*32 + qd*8]);
    #pragma unroll
    for(int nf=0;nf<8;nf++) bfv[nf] = ldfrag(&Bs[(wn*128+nf*16+ln)*32 + qd*8]);
    #pragma unroll
    for(int mf=0;mf<4;mf++)
      #pragma unroll
      for(int nf=0;nf<8;nf++)
        acc[mf][nf] = __builtin_amdgcn_mfma_f32_16x16x32_bf16(af[mf], bfv[nf], acc[mf][nf], 0,0,0);
    __syncthreads();
    ra0 = rb0; ra1 = rb1;
  }
  for(int nf=0;nf<8;nf++){
    int n = wn*128 + nf*16 + ln;
    float bias = bq[n];
    for(int mf=0;mf<4;mf++){
      for(int r=0;r<4;r++){
        int ml = wm*64 + mf*16 + qd*4 + r;
        qb[((size_t)(mt*128+ml))*256 + n] = f2bf(acc[mf][nf][r]+bias);
      }
    }
  }
}

// ---------------- K6: k,v = ctx @ {wk,wv}^T + b, 64x64 tiles, 160 blocks ----------------
__global__ __launch_bounds__(256) void k_kvproj(const u16* __restrict__ ctxB, const u16* __restrict__ wkvB,
    const float* __restrict__ bk, const float* __restrict__ bv,
    u16* __restrict__ kb, u16* __restrict__ vT){
  __shared__ u16 As[64*128];
  __shared__ u16 Bs[64*128];
  int bid = blockIdx.x;
  int nt = bid & 7, mt = bid >> 3;
  int n0 = nt*64, m0 = mt*64;
  int tid=threadIdx.x, w=tid>>6, lane=tid&63, ln=lane&15, qd=lane>>4;
  int wm = w&1, wn = w>>1;
  f32x4 acc[2][2]={};
  for(int kt=0;kt<6;kt++){
    #pragma unroll
    for(int r=0;r<4;r++){
      int c = r*256 + tid;
      int row = c>>4, atom = c&15;
      g2l16(ctxB + ((size_t)(m0+row)*768 + kt*128 + atom*8), &As[c*8]);
      g2l16(wkvB + ((size_t)(n0+row)*768 + kt*128 + atom*8), &Bs[c*8]);
    }
    __syncthreads();
    #pragma unroll
    for(int kk=0;kk<4;kk++){
      bf16x8 af[2], bfv[2];
      #pragma unroll
      for(int mf=0;mf<2;mf++) af[mf]=ldfrag(&As[(wm*32+mf*16+ln)*128 + kk*32 + qd*8]);
      #pragma unroll
      for(int nf=0;nf<2;nf++) bfv[nf]=ldfrag(&Bs[(wn*32+nf*16+ln)*128 + kk*32 + qd*8]);
      #pragma unroll
      for(int mf=0;mf<2;mf++)
        #pragma unroll
        for(int nf=0;nf<2;nf++)
          acc[mf][nf]=__builtin_amdgcn_mfma_f32_16x16x32_bf16(af[mf],bfv[nf],acc[mf][nf],0,0,0);
    }
    __syncthreads();
  }
  for(int mf=0;mf<2;mf++) for(int nf=0;nf<2;nf++){
    int ng = n0 + wn*32 + nf*16 + ln;
    float bias = ng<256 ? bk[ng] : bv[ng-256];
    for(int r=0;r<4;r++){
      int mg = m0 + wm*32 + mf*16 + qd*4 + r;
      if(mg<1232){
        float v=acc[mf][nf][r]+bias;
        int bb=mg/77, l=mg-bb*77;
        if(ng<256) kb[((size_t)(bb*77+l))*256+ng]=f2bf(v);
        else vT[((size_t)(bb*256+(ng-256)))*96 + l]=f2bf(v);
      }
    }
  }
}

// ---------------- K7: attention, rewritten: 3 barriers, in-register softmax ----------------
// K staged once (atom-major, conflict-free), Q in registers, S-loop barrier-free;
// softmax fully in-register (5-reg in-lane reduce + 4 shfl_xor over the 16-lane col group,
// all 256 threads active); V staged once into the K buffer; PV barrier-free.
__global__ __launch_bounds__(256, 2) void k_attn(const u16* __restrict__ qg, const u16* __restrict__ kb,
    const u16* __restrict__ vT, u16* __restrict__ ob){
  __shared__ u16 KVf[3072*8];     // 49,152 B. K-phase: [kt(8)][qd(4)][80 rows][8]; V-phase: [(nh*3+kt2)(6)][qd(4)][128 co][8]
  __shared__ u16 Pb[128*104];     // 26,624 B, P (unnormalized) bf16, k padded to 96
  __shared__ float invr[128];
  int bid=blockIdx.x; int b=bid>>5, qt=bid&31; int p0=qt*128;
  int tid=threadIdx.x, w=tid>>6, lane=tid&63, ln=lane&15, qd=lane>>4;

  // ---- stage all K (rows 77..79 clamp-staged from row 76; masked later) ----
  #pragma unroll
  for(int j=0;j<10;j++){
    int c = tid + j*256;                  // 0..2559
    int kt = c/320, rem = c - kt*320;
    int q2 = rem/80, l = rem - q2*80;
    int ls = l<77 ? l : 76;
    g2l16(kb + ((size_t)(b*77+ls)*256 + kt*32 + q2*8), &KVf[(size_t)c*8]);
  }
  // ---- Q straight to registers (16 frags; rows this wave owns) ----
  bf16x8 qf[2][8];
  #pragma unroll
  for(int mf=0;mf<2;mf++){
    const u16* qsrc = qg + ((size_t)(b*HW_ + p0 + w*32 + mf*16 + ln))*256 + qd*8;
    #pragma unroll
    for(int kt=0;kt<8;kt++) qf[mf][kt] = ldfrag(qsrc + kt*32);
  }
  __syncthreads();                        // barrier 1: K staged

  // ---- S = Q K^T, no barriers ----
  f32x4 Sa[2][5]={};
  #pragma unroll
  for(int kt=0;kt<8;kt++){
    bf16x8 kf[5];
    #pragma unroll
    for(int nf=0;nf<5;nf++) kf[nf]=ldfrag(&KVf[((size_t)kt*320 + qd*80 + nf*16+ln)*8]);
    #pragma unroll
    for(int mf=0;mf<2;mf++)
      #pragma unroll
      for(int nf=0;nf<5;nf++)
        Sa[mf][nf]=__builtin_amdgcn_mfma_f32_16x16x32_bf16(qf[mf][kt],kf[nf],Sa[mf][nf],0,0,0);
  }
  // mask clamp-staged cols 77..79 (col = 64+ln for nf=4)
  if(ln>=13){
    #pragma unroll
    for(int mf=0;mf<2;mf++)
      #pragma unroll
      for(int r=0;r<4;r++) Sa[mf][4][r] = -1e30f;
  }
  // ---- in-register softmax: row = w*32+mf*16+qd*4+r lives on the 16-lane ln-group ----
  float mrow[2][4];
  #pragma unroll
  for(int mf=0;mf<2;mf++)
    #pragma unroll
    for(int r=0;r<4;r++){
      float m = Sa[mf][0][r];
      #pragma unroll
      for(int nf=1;nf<5;nf++) m = fmaxf(m, Sa[mf][nf][r]);
      mrow[mf][r]=m;
    }
  #pragma unroll
  for(int off=1;off<16;off<<=1)
    #pragma unroll
    for(int mf=0;mf<2;mf++)
      #pragma unroll
      for(int r=0;r<4;r++) mrow[mf][r] = fmaxf(mrow[mf][r], __shfl_xor(mrow[mf][r], off, 64));
  float rs[2][4]={};
  u16 pe[2][5][4];
  #pragma unroll
  for(int mf=0;mf<2;mf++)
    #pragma unroll
    for(int nf=0;nf<5;nf++)
      #pragma unroll
      for(int r=0;r<4;r++){
        float e = __expf((Sa[mf][nf][r]-mrow[mf][r])*0.0625f);
        rs[mf][r]+=e; pe[mf][nf][r]=f2bf(e);
      }
  #pragma unroll
  for(int off=1;off<16;off<<=1)
    #pragma unroll
    for(int mf=0;mf<2;mf++)
      #pragma unroll
      for(int r=0;r<4;r++) rs[mf][r] += __shfl_xor(rs[mf][r], off, 64);
  #pragma unroll
  for(int mf=0;mf<2;mf++)
    #pragma unroll
    for(int nf=0;nf<5;nf++)
      #pragma unroll
      for(int r=0;r<4;r++) Pb[(w*32+mf*16+qd*4+r)*104 + nf*16+ln] = pe[mf][nf][r];
  {
    // zero pad cols 80..95 for all 128 rows
    int row = tid>>1, j0 = (tid&1)*8;
    u16x8 z = {0,0,0,0,0,0,0,0};
    *(u16x8*)&Pb[row*104 + 80 + j0] = z;
  }
  if(ln==0){
    #pragma unroll
    for(int mf=0;mf<2;mf++)
      #pragma unroll
      for(int r=0;r<4;r++) invr[w*32+mf*16+qd*4+r] = 1.f/rs[mf][r];
  }
  __syncthreads();                        // barrier 2: K reads + P writes done

  // ---- stage all V into KVf ----
  #pragma unroll
  for(int j=0;j<12;j++){
    int c = tid + j*256;                  // 0..3071
    int g = c>>7, co = c&127;
    int q2 = g&3, s5 = g>>2;              // s5 = nh*3+kt2
    int nh2 = s5>2 ? 1 : 0, kt2 = s5 - 3*nh2;
    g2l16(vT + ((size_t)(b*256 + nh2*128 + co)*96 + kt2*32 + q2*8), &KVf[(size_t)c*8]);
  }
  __syncthreads();                        // barrier 3: V staged

  // ---- O = P V, no barriers ----
  #pragma unroll
  for(int nh=0;nh<2;nh++){
    f32x4 Oa[2][8]={};
    #pragma unroll
    for(int kt2=0;kt2<3;kt2++){
      bf16x8 pa[2], vf[8];
      #pragma unroll
      for(int mf=0;mf<2;mf++) pa[mf]=ldfrag(&Pb[(w*32+mf*16+ln)*104 + kt2*32+qd*8]);
      #pragma unroll
      for(int nf=0;nf<8;nf++) vf[nf]=ldfrag(&KVf[(((size_t)(nh*3+kt2)*4+qd)*128 + nf*16+ln)*8]);
      #pragma unroll
      for(int mf=0;mf<2;mf++)
        #pragma unroll
        for(int nf=0;nf<8;nf++)
          Oa[mf][nf]=__builtin_amdgcn_mfma_f32_16x16x32_bf16(pa[mf],vf[nf],Oa[mf][nf],0,0,0);
    }
    #pragma unroll
    for(int mf=0;mf<2;mf++){
      #pragma unroll
      for(int r=0;r<4;r++){
        int ml=w*32+mf*16+qd*4+r;
        float inv = invr[ml];
        #pragma unroll
        for(int nf=0;nf<8;nf++){
          int nl=nh*128+nf*16+ln;
          ob[((size_t)(b*HW_+p0+ml))*256+nl]=f2bf(Oa[mf][nf][r]*inv);
        }
      }
    }
  }
}

// ---------------- K8: out = x + (wo @ o^T) + bo, written NCHW ----------------
__global__ __launch_bounds__(256) void k_oproj(const u16* __restrict__ ob, const u16* __restrict__ woB,
    const float* __restrict__ bo, const float* __restrict__ x, float* __restrict__ outp){
  __shared__ u16 As[128*32];
  __shared__ u16 Bs[128*32];
  int bid=blockIdx.x;
  int b=bid>>6; int rr=bid&63; int cm=rr>>5, pt=rr&31;
  int c0=cm*128, p0=pt*128;
  int tid=threadIdx.x, w=tid>>6, lane=tid&63, ln=lane&15, qd=lane>>4, wm=w>>1, wn=w&1;
  int srow=tid>>2, koff=(tid&3)*8;
  f32x4 acc[4][4]={};
  for(int kt=0;kt<8;kt++){
    for(int j=0;j<2;j++){
      int m=srow+j*64;
      g2l16(woB + ((size_t)(c0+m)*256 + kt*32+koff),        &As[(size_t)tid*8+j*2048]);
      g2l16(ob  + ((size_t)(b*HW_+p0+m)*256 + kt*32+koff),  &Bs[(size_t)tid*8+j*2048]);
    }
    __syncthreads();
    bf16x8 af[4], bfv[4];
    for(int mf=0;mf<4;mf++) af[mf]=ldfrag(&As[(wm*64+mf*16+ln)*32+qd*8]);
    for(int nf=0;nf<4;nf++) bfv[nf]=ldfrag(&Bs[(wn*64+nf*16+ln)*32+qd*8]);
    for(int mf=0;mf<4;mf++) for(int nf=0;nf<4;nf++)
      acc[mf][nf]=__builtin_amdgcn_mfma_f32_16x16x32_bf16(af[mf],bfv[nf],acc[mf][nf],0,0,0);
    __syncthreads();
  }
  for(int mf=0;mf<4;mf++) for(int r=0;r<4;r++){
    int cl=c0+wm*64+mf*16+qd*4+r;
    float bias=bo[cl];
    for(int nf=0;nf<4;nf++){
      int pl=p0+wn*64+nf*16+ln;
      size_t idx=((size_t)(b*C_+cl))*HW_+pl;
      outp[idx]=x[idx]+acc[mf][nf][r]+bias;
    }
  }
}

extern "C" void kernel_launch(void* const* d_in, const int* in_sizes, int n_in,
                              void* d_out, int out_size, void* d_ws, size_t ws_size,
                              hipStream_t stream){
  const float* x      = (const float*)d_in[0];
  const float* ctx    = (const float*)d_in[1];
  const float* conv_w = (const float*)d_in[2];
  const float* conv_b = (const float*)d_in[3];
  const float* gnw    = (const float*)d_in[4];
  const float* gnb    = (const float*)d_in[5];
  const float* wq     = (const float*)d_in[6];
  const float* bq     = (const float*)d_in[7];
  const float* wk     = (const float*)d_in[8];
  const float* bk     = (const float*)d_in[9];
  const float* wv     = (const float*)d_in[10];
  const float* bv     = (const float*)d_in[11];
  const float* wo     = (const float*)d_in[12];
  const float* bo     = (const float*)d_in[13];
  char* ws = (char*)d_ws;
  u16* xpT  = (u16*)(ws + 0);            // 35,684,352 ; reused as q after conv
  u16* wBt  = (u16*)(ws + 35684352);     //  1,179,648
  u16* wqB  = (u16*)(ws + 36864000);     //    131,072
  u16* wkvB = (u16*)(ws + 36995072);     //    786,432
  u16* woB  = (u16*)(ws + 37781504);     //    131,072
  u16* ctxB = (u16*)(ws + 37912576);     //  1,892,352 (+74KB OOB read slack into hbuf)
  u16* hbuf = (u16*)(ws + 39804928);     // 33,554,432 (raw conv output)
  u16* kbv  = (u16*)(ws + 73359360);     //    630,784
  u16* vT   = (u16*)(ws + 73990144);     //    786,432
  u16* obuf = (u16*)(ws + 74776576);     // 33,554,432
  float* stats = (float*)(ws + 108331008); // 2048
  u16* qb = xpT;
  float* outp = (float*)d_out;

  k_prep  <<<9106, 256, 0, stream>>>(x, xpT, conv_w, wq, wo, wk, wv, ctx, wBt, wqB, woB, wkvB, ctxB, stats);
  k_conv  <<<1024, 256, 0, stream>>>(xpT, wBt, conv_b, hbuf, stats);
  k_qgn   <<<512,  256, 0, stream>>>(hbuf, wqB, stats, gnw, gnb, bq, qb);
  k_kvproj<<<160,  256, 0, stream>>>(ctxB, wkvB, bk, bv, kbv, vT);
  k_attn  <<<512,  256, 0, stream>>>(qb, kbv, vT, obuf);
  k_oproj <<<1024, 256, 0, stream>>>(obuf, woB, bo, x, outp);
}

// Round 6
// 338.834 us; speedup vs baseline: 1.2543x; 1.0811x over previous
//
#include <hip/hip_runtime.h>
#include <stdint.h>

#define B_  16
#define C_  256
#define HW_ 4096
#define Hp  66
#define PP  4356   // 66*66
#define EPS_ 1e-5f

typedef unsigned short u16;
typedef unsigned int   u32;
typedef __attribute__((ext_vector_type(4))) float  f32x4;
typedef __attribute__((ext_vector_type(8))) __bf16 bf16x8;
typedef __attribute__((ext_vector_type(8))) u16    u16x8;

__device__ __forceinline__ float bf2f(u16 u){ u32 x = ((u32)u)<<16; float f; __builtin_memcpy(&f,&x,4); return f; }
__device__ __forceinline__ u16 f2bf(float f){ u32 x; __builtin_memcpy(&x,&f,4); u32 r = x + 0x7fffu + ((x>>16)&1u); return (u16)(r>>16); }

__device__ __forceinline__ void g2l16(const void* g, void* l){
  __builtin_amdgcn_global_load_lds((__attribute__((address_space(1))) void*)(void*)g,
                                   (__attribute__((address_space(3))) void*)l, 16, 0, 0);
}
__device__ __forceinline__ bf16x8 ldfrag(const u16* p){
  u16x8 r = *(const u16x8*)p;
  return __builtin_bit_cast(bf16x8, r);
}

// ---------------- K0: pad+transpose x AND repack weights (merged, block-range split) -----
// Layouts (conflict-free atom-major LDS staging for k_conv):
//   xpT: [b][ci(8)][atom(4)][PP pixels][8ch]
//   wBt: [ci(8)][tap(9)][atom(4)][co(256)][8ch]
__global__ __launch_bounds__(256) void k_prep(const float* __restrict__ x, u16* __restrict__ xpT,
    const float* __restrict__ conv_w, const float* __restrict__ wq, const float* __restrict__ wo,
    const float* __restrict__ wk, const float* __restrict__ wv, const float* __restrict__ ctx,
    u16* __restrict__ wBt, u16* __restrict__ wqB, u16* __restrict__ woB,
    u16* __restrict__ wkvB, u16* __restrict__ ctxB, float* __restrict__ stats){
  __shared__ float Lt[64*65];
  int bid = blockIdx.x; int tid = threadIdx.x;
  if(bid >= 1056){
    int i = (bid-1056)*256 + tid;
    if(i < 589824){
      int j = i&7, co = (i>>3)&255, atom = (i>>11)&3, g = i>>13;   // g in [0,72)
      int t = g%9, cic = g/9;
      int ciF = cic*32 + atom*8 + j;
      wBt[i] = f2bf(conv_w[(co*256+ciF)*9 + t]); return;
    }
    i -= 589824;
    if(i < 65536){ wqB[i] = f2bf(wq[i]); return; } i -= 65536;
    if(i < 65536){ woB[i] = f2bf(wo[i]); return; } i -= 65536;
    if(i < 196608){ wkvB[i] = f2bf(wk[i]); return; } i -= 196608;
    if(i < 196608){ wkvB[196608+i] = f2bf(wv[i]); return; } i -= 196608;
    if(i < 946176){ ctxB[i] = f2bf(ctx[i]); return; } i -= 946176;
    if(i < 512){ stats[i] = 0.f; }
    return;
  }
  int b = bid/66, hh = bid - b*66;
  if(hh==0 || hh==65){
    for(int i=tid;i<32*264;i+=256){
      int pl = i/264, off = i - pl*264;
      u32* p = (u32*)(xpT + ((size_t)(b*32+pl)*PP + (size_t)hh*Hp)*8);
      p[off] = 0u;
    }
    return;
  }
  {
    int pl = tid>>3, q = tid&7;
    size_t base = ((size_t)(b*32+pl)*PP + (size_t)hh*Hp + (q>=4?65:0))*8;
    ((u32*)(xpT + base))[q&3] = 0u;
  }
  int h = hh-1;
  for(int cc=0; cc<4; cc++){
    int c0=cc*64;
    int ci = tid>>2, w0 = (tid&3)*16;
    const float* xs = x + ((size_t)(b*C_ + c0+ci)*HW_) + h*64 + w0;
    for(int j=0;j<4;j++){
      float4 v = *(const float4*)(xs + j*4);
      Lt[ci*65 + w0 + j*4 + 0] = v.x;
      Lt[ci*65 + w0 + j*4 + 1] = v.y;
      Lt[ci*65 + w0 + j*4 + 2] = v.z;
      Lt[ci*65 + w0 + j*4 + 3] = v.w;
    }
    __syncthreads();
    int w = tid>>2, cj = (tid&3)*16;
    union { u16 u[16]; uint4 v[2]; } outu;
    for(int j=0;j<16;j++) outu.u[j] = f2bf(Lt[(cj+j)*65 + w]);
    int chan = c0 + cj;
    int cic = chan>>5, at0 = (chan>>3)&3;
    u16* dst = xpT + (((size_t)(b*8+cic)*4 + at0)*PP + (size_t)hh*Hp + w + 1)*8;
    *(uint4*)dst = outu.v[0];
    *(uint4*)(dst + (size_t)PP*8) = outu.v[1];
    __syncthreads();
  }
}

// ---------------- K2: conv implicit GEMM (best measured variant: R2, 122.7us) ----------------
__global__ __launch_bounds__(256, 3) void k_conv(const u16* __restrict__ xpT, const u16* __restrict__ wBt,
    const float* __restrict__ conv_b, u16* __restrict__ h, float* __restrict__ stats){
  __shared__ u16 As[2][264*32];   // 33,792 B
  __shared__ u16 Bs[2][128*32];   // 16,384 B
  int bid0 = blockIdx.x;
  int l = (bid0 & 7)*128 + (bid0 >> 3);    // chunked XCD swizzle, 1024 % 8 == 0 (bijective)
  int b = l >> 6, hp = (l >> 1) & 31, nh = l & 1;
  int tid = threadIdx.x;
  int w = tid>>6, lane = tid&63, ln = lane&15, qd = lane>>4;
  int wm = w&1, wn = w>>1;
  f32x4 acc[4][4] = {};
  int hr_[4], wp_[4];
  #pragma unroll
  for(int mf=0;mf<4;mf++){ int p = wm*64 + mf*16 + ln; hr_[mf] = p>>6; wp_[mf] = p&63; }

  #pragma unroll
  for(int r=0;r<5;r++){
    int c = r*256 + tid;
    if(c < 1056){
      int atom = c/264, ipix = c - atom*264;
      g2l16(xpT + (((size_t)(b*8+0)*4 + atom)*PP + hp*132 + ipix)*8, &As[0][c*8]);
    }
  }
  #pragma unroll
  for(int r=0;r<2;r++){
    int c = r*256 + tid;
    int atom = c>>7, col = c&127;
    g2l16(wBt + ((size_t)atom*2048 + (nh*128+col)*8), &Bs[0][c*8]);
  }
  __syncthreads();

  int cb = 0;
  for(int ci=0; ci<8; ci++){
    int ca = ci&1;
    for(int t=0;t<9;t++){
      int tn = t+1, cin = ci;
      if(tn==9){ tn=0; cin=ci+1; }
      if(cin < 8){
        #pragma unroll
        for(int r=0;r<2;r++){
          int c = r*256 + tid;
          int atom = c>>7, col = c&127;
          g2l16(wBt + (((size_t)(cin*9+tn)*4 + atom)*2048 + (nh*128+col)*8), &Bs[cb^1][c*8]);
        }
      }
      if(t<5 && ci<7){
        int c = t*256 + tid;
        if(c < 1056){
          int atom = c/264, ipix = c - atom*264;
          g2l16(xpT + (((size_t)(b*8+ci+1)*4 + atom)*PP + hp*132 + ipix)*8, &As[ca^1][c*8]);
        }
      }
      int dy = (t*11)>>5, dx = t - dy*3;
      bf16x8 af[4], bfv[4];
      #pragma unroll
      for(int mf=0;mf<4;mf++){
        int ipix = (hr_[mf]+dy)*66 + wp_[mf] + dx;
        af[mf] = ldfrag(&As[ca][(qd*264 + ipix)*8]);
      }
      #pragma unroll
      for(int nf=0;nf<4;nf++) bfv[nf] = ldfrag(&Bs[cb][(qd*128 + wn*64+nf*16+ln)*8]);
      #pragma unroll
      for(int mf=0;mf<4;mf++)
        #pragma unroll
        for(int nf=0;nf<4;nf++)
          acc[mf][nf] = __builtin_amdgcn_mfma_f32_16x16x32_bf16(af[mf], bfv[nf], acc[mf][nf], 0,0,0);
      __syncthreads();
      cb ^= 1;
    }
  }
  float s[2]={0,0}, q[2]={0,0};
  int p0 = hp*128;
  for(int nf=0;nf<4;nf++){
    int n = nh*128 + wn*64 + nf*16 + ln;
    float bias = conv_b[n];
    for(int mf=0;mf<4;mf++){
      for(int r=0;r<4;r++){
        int p = wm*64 + mf*16 + qd*4 + r;
        float v = acc[mf][nf][r] + bias;
        h[((size_t)(b*HW_ + p0 + p))*C_ + n] = f2bf(v);
        s[nf>>1]+=v; q[nf>>1]+=v*v;
      }
    }
  }
  for(int off=32;off>=1;off>>=1){
    #pragma unroll
    for(int g=0;g<2;g++){ s[g]+=__shfl_down(s[g],off,64); q[g]+=__shfl_down(q[g],off,64); }
  }
  if(lane==0){
    #pragma unroll
    for(int g=0;g<2;g++){
      int gg = nh*4 + wn*2 + g;
      atomicAdd(&stats[(b*8 + gg)*2+0], s[g]);
      atomicAdd(&stats[(b*8 + gg)*2+1], q[g]);
    }
  }
}

// ---------------- K5: fused GN+SiLU+qproj: q = silu(gn(h)) @ wq^T + bq ----------------
__global__ __launch_bounds__(256, 2) void k_qgn(const u16* __restrict__ hbuf, const u16* __restrict__ wqB,
    const float* __restrict__ stats, const float* __restrict__ gnw, const float* __restrict__ gnb,
    const float* __restrict__ bq, u16* __restrict__ qb){
  __shared__ u16 As[128*32];
  __shared__ u16 Bs[256*32];
  int mt = blockIdx.x;
  int b = mt >> 5;
  int tid = threadIdx.x;
  int w = tid>>6, lane = tid&63, ln = lane&15, qd = lane>>4;
  int wm = w&1, wn = w>>1;
  int pr = tid>>1, half = tid&1;
  const u16* hsrc = hbuf + ((size_t)(mt*128+pr))*256 + half*16;
  f32x4 acc[4][8] = {};
  uint4 ra0, ra1, rb0, rb1;
  ra0 = *(const uint4*)(hsrc);
  ra1 = *(const uint4*)(hsrc + 8);
  for(int kt=0; kt<8; kt++){
    float sm = stats[(b*8+kt)*2], qm = stats[(b*8+kt)*2+1];
    float mean = sm*(1.f/131072.f);
    float rstd = rsqrtf(qm*(1.f/131072.f) - mean*mean + EPS_);
    int c0 = kt*32 + half*16;
    float4 gw0 = *(const float4*)(gnw+c0), gw1 = *(const float4*)(gnw+c0+4);
    float4 gw2 = *(const float4*)(gnw+c0+8), gw3 = *(const float4*)(gnw+c0+12);
    float4 gb0 = *(const float4*)(gnb+c0), gb1 = *(const float4*)(gnb+c0+4);
    float4 gb2 = *(const float4*)(gnb+c0+8), gb3 = *(const float4*)(gnb+c0+12);
    float gwv[16] = {gw0.x,gw0.y,gw0.z,gw0.w, gw1.x,gw1.y,gw1.z,gw1.w,
                     gw2.x,gw2.y,gw2.z,gw2.w, gw3.x,gw3.y,gw3.z,gw3.w};
    float gbv[16] = {gb0.x,gb0.y,gb0.z,gb0.w, gb1.x,gb1.y,gb1.z,gb1.w,
                     gb2.x,gb2.y,gb2.z,gb2.w, gb3.x,gb3.y,gb3.z,gb3.w};
    u16 inu[16];
    ((uint4*)inu)[0] = ra0; ((uint4*)inu)[1] = ra1;
    u16 outu[16];
    #pragma unroll
    for(int j=0;j<16;j++){
      float v = bf2f(inu[j]);
      v = (v-mean)*rstd*gwv[j] + gbv[j];
      float s = v/(1.f+__expf(-v));
      outu[j] = f2bf(s);
    }
    u16* adst = &As[pr*32 + half*16];
    ((uint4*)adst)[0] = ((uint4*)outu)[0];
    ((uint4*)adst)[1] = ((uint4*)outu)[1];
    #pragma unroll
    for(int r=0;r<4;r++){
      int c = r*256 + tid;
      int co = c>>2, atom = c&3;
      g2l16(wqB + (size_t)co*256 + kt*32 + atom*8, &Bs[c*8]);
    }
    if(kt<7){
      rb0 = *(const uint4*)(hsrc + (kt+1)*32);
      rb1 = *(const uint4*)(hsrc + (kt+1)*32 + 8);
    }
    __syncthreads();
    bf16x8 af[4], bfv[8];
    #pragma unroll
    for(int mf=0;mf<4;mf++) af[mf] = ldfrag(&As[(wm*64+mf*16+ln)*32 + qd*8]);
    #pragma unroll
    for(int nf=0;nf<8;nf++) bfv[nf] = ldfrag(&Bs[(wn*128+nf*16+ln)*32 + qd*8]);
    #pragma unroll
    for(int mf=0;mf<4;mf++)
      #pragma unroll
      for(int nf=0;nf<8;nf++)
        acc[mf][nf] = __builtin_amdgcn_mfma_f32_16x16x32_bf16(af[mf], bfv[nf], acc[mf][nf], 0,0,0);
    __syncthreads();
    ra0 = rb0; ra1 = rb1;
  }
  for(int nf=0;nf<8;nf++){
    int n = wn*128 + nf*16 + ln;
    float bias = bq[n];
    for(int mf=0;mf<4;mf++){
      for(int r=0;r<4;r++){
        int ml = wm*64 + mf*16 + qd*4 + r;
        qb[((size_t)(mt*128+ml))*256 + n] = f2bf(acc[mf][nf][r]+bias);
      }
    }
  }
}

// ---------------- K6: k,v = ctx @ {wk,wv}^T + b, 64x64 tiles, 160 blocks ----------------
__global__ __launch_bounds__(256) void k_kvproj(const u16* __restrict__ ctxB, const u16* __restrict__ wkvB,
    const float* __restrict__ bk, const float* __restrict__ bv,
    u16* __restrict__ kb, u16* __restrict__ vT){
  __shared__ u16 As[64*128];
  __shared__ u16 Bs[64*128];
  int bid = blockIdx.x;
  int nt = bid & 7, mt = bid >> 3;
  int n0 = nt*64, m0 = mt*64;
  int tid=threadIdx.x, w=tid>>6, lane=tid&63, ln=lane&15, qd=lane>>4;
  int wm = w&1, wn = w>>1;
  f32x4 acc[2][2]={};
  for(int kt=0;kt<6;kt++){
    #pragma unroll
    for(int r=0;r<4;r++){
      int c = r*256 + tid;
      int row = c>>4, atom = c&15;
      g2l16(ctxB + ((size_t)(m0+row)*768 + kt*128 + atom*8), &As[c*8]);
      g2l16(wkvB + ((size_t)(n0+row)*768 + kt*128 + atom*8), &Bs[c*8]);
    }
    __syncthreads();
    #pragma unroll
    for(int kk=0;kk<4;kk++){
      bf16x8 af[2], bfv[2];
      #pragma unroll
      for(int mf=0;mf<2;mf++) af[mf]=ldfrag(&As[(wm*32+mf*16+ln)*128 + kk*32 + qd*8]);
      #pragma unroll
      for(int nf=0;nf<2;nf++) bfv[nf]=ldfrag(&Bs[(wn*32+nf*16+ln)*128 + kk*32 + qd*8]);
      #pragma unroll
      for(int mf=0;mf<2;mf++)
        #pragma unroll
        for(int nf=0;nf<2;nf++)
          acc[mf][nf]=__builtin_amdgcn_mfma_f32_16x16x32_bf16(af[mf],bfv[nf],acc[mf][nf],0,0,0);
    }
    __syncthreads();
  }
  for(int mf=0;mf<2;mf++) for(int nf=0;nf<2;nf++){
    int ng = n0 + wn*32 + nf*16 + ln;
    float bias = ng<256 ? bk[ng] : bv[ng-256];
    for(int r=0;r<4;r++){
      int mg = m0 + wm*32 + mf*16 + qd*4 + r;
      if(mg<1232){
        float v=acc[mf][nf][r]+bias;
        int bb=mg/77, l=mg-bb*77;
        if(ng<256) kb[((size_t)(bb*77+l))*256+ng]=f2bf(v);
        else vT[((size_t)(bb*256+(ng-256)))*96 + l]=f2bf(v);
      }
    }
  }
}

// ---------------- K7: attention FUSED with o-projection + residual ----------------
// Phases: [K stage | Q->regs] S QK^T (no barriers), in-reg softmax, P->LDS;
// [V stage] PV both nh halves (Oa in regs, no barriers); O (normalized bf16) -> LDS
// Ol[128][264] (264-stride: 2-way bank aliasing = free), overlaying dead K/V/P;
// wo-GEMM: A = woB direct global->reg (L2-hot 128KB), B = O from LDS;
// epilogue writes outp = x + O@wo^T + bo directly (obuf + k_oproj eliminated).
__global__ __launch_bounds__(256, 2) void k_attn(const u16* __restrict__ qg, const u16* __restrict__ kb,
    const u16* __restrict__ vT, const u16* __restrict__ woB, const float* __restrict__ bo,
    const float* __restrict__ x, float* __restrict__ outp){
  __shared__ u16 SM[37888];       // 75,776 B shared pool
  __shared__ float invr[128];
  u16* KVf = SM;                  // K-phase: [kt8][qd4][80][8] (40,960 u16); V-phase: [s6][qd4][128][8] (24,576 u16)
  u16* Pb  = SM + 24576;          // [128][104] = 13,312 u16
  u16* Ol  = SM;                  // O bf16 [128 px][264 pad] = 33,792 u16 (overlays KVf+Pb after PV)
  int bid=blockIdx.x; int b=bid>>5, qt=bid&31; int p0=qt*128;
  int tid=threadIdx.x, w=tid>>6, lane=tid&63, ln=lane&15, qd=lane>>4;

  // ---- stage all K (rows 77..79 clamp-staged from row 76; masked later) ----
  #pragma unroll
  for(int j=0;j<10;j++){
    int c = tid + j*256;                  // 0..2559
    int kt = c/320, rem = c - kt*320;
    int q2 = rem/80, l = rem - q2*80;
    int ls = l<77 ? l : 76;
    g2l16(kb + ((size_t)(b*77+ls)*256 + kt*32 + q2*8), &KVf[(size_t)c*8]);
  }
  // ---- Q straight to registers ----
  bf16x8 qf[2][8];
  #pragma unroll
  for(int mf=0;mf<2;mf++){
    const u16* qsrc = qg + ((size_t)(b*HW_ + p0 + w*32 + mf*16 + ln))*256 + qd*8;
    #pragma unroll
    for(int kt=0;kt<8;kt++) qf[mf][kt] = ldfrag(qsrc + kt*32);
  }
  __syncthreads();                        // barrier 1: K staged

  // ---- S = Q K^T ----
  f32x4 Sa[2][5]={};
  #pragma unroll
  for(int kt=0;kt<8;kt++){
    bf16x8 kf[5];
    #pragma unroll
    for(int nf=0;nf<5;nf++) kf[nf]=ldfrag(&KVf[((size_t)kt*320 + qd*80 + nf*16+ln)*8]);
    #pragma unroll
    for(int mf=0;mf<2;mf++)
      #pragma unroll
      for(int nf=0;nf<5;nf++)
        Sa[mf][nf]=__builtin_amdgcn_mfma_f32_16x16x32_bf16(qf[mf][kt],kf[nf],Sa[mf][nf],0,0,0);
  }
  if(ln>=13){
    #pragma unroll
    for(int mf=0;mf<2;mf++)
      #pragma unroll
      for(int r=0;r<4;r++) Sa[mf][4][r] = -1e30f;
  }
  // ---- in-register softmax ----
  float mrow[2][4];
  #pragma unroll
  for(int mf=0;mf<2;mf++)
    #pragma unroll
    for(int r=0;r<4;r++){
      float m = Sa[mf][0][r];
      #pragma unroll
      for(int nf=1;nf<5;nf++) m = fmaxf(m, Sa[mf][nf][r]);
      mrow[mf][r]=m;
    }
  #pragma unroll
  for(int off=1;off<16;off<<=1)
    #pragma unroll
    for(int mf=0;mf<2;mf++)
      #pragma unroll
      for(int r=0;r<4;r++) mrow[mf][r] = fmaxf(mrow[mf][r], __shfl_xor(mrow[mf][r], off, 64));
  float rs[2][4]={};
  u16 pe[2][5][4];
  #pragma unroll
  for(int mf=0;mf<2;mf++)
    #pragma unroll
    for(int nf=0;nf<5;nf++)
      #pragma unroll
      for(int r=0;r<4;r++){
        float e = __expf((Sa[mf][nf][r]-mrow[mf][r])*0.0625f);
        rs[mf][r]+=e; pe[mf][nf][r]=f2bf(e);
      }
  #pragma unroll
  for(int off=1;off<16;off<<=1)
    #pragma unroll
    for(int mf=0;mf<2;mf++)
      #pragma unroll
      for(int r=0;r<4;r++) rs[mf][r] += __shfl_xor(rs[mf][r], off, 64);
  #pragma unroll
  for(int mf=0;mf<2;mf++)
    #pragma unroll
    for(int nf=0;nf<5;nf++)
      #pragma unroll
      for(int r=0;r<4;r++) Pb[(w*32+mf*16+qd*4+r)*104 + nf*16+ln] = pe[mf][nf][r];
  {
    int row = tid>>1, j0 = (tid&1)*8;
    u16x8 z = {0,0,0,0,0,0,0,0};
    *(u16x8*)&Pb[row*104 + 80 + j0] = z;
  }
  if(ln==0){
    #pragma unroll
    for(int mf=0;mf<2;mf++)
      #pragma unroll
      for(int r=0;r<4;r++) invr[w*32+mf*16+qd*4+r] = 1.f/rs[mf][r];
  }
  __syncthreads();                        // barrier 2: K reads + P writes done

  // ---- stage all V into KVf ----
  #pragma unroll
  for(int j=0;j<12;j++){
    int c = tid + j*256;                  // 0..3071
    int g = c>>7, co = c&127;
    int q2 = g&3, s5 = g>>2;              // s5 = nh*3+kt2
    int nh2 = s5>2 ? 1 : 0, kt2 = s5 - 3*nh2;
    g2l16(vT + ((size_t)(b*256 + nh2*128 + co)*96 + kt2*32 + q2*8), &KVf[(size_t)c*8]);
  }
  __syncthreads();                        // barrier 3: V staged

  // ---- O = P V, both nh halves, Oa in registers ----
  f32x4 Oa[2][2][8]={};
  #pragma unroll
  for(int nh=0;nh<2;nh++){
    #pragma unroll
    for(int kt2=0;kt2<3;kt2++){
      bf16x8 pa[2], vf[8];
      #pragma unroll
      for(int mf=0;mf<2;mf++) pa[mf]=ldfrag(&Pb[(w*32+mf*16+ln)*104 + kt2*32+qd*8]);
      #pragma unroll
      for(int nf=0;nf<8;nf++) vf[nf]=ldfrag(&KVf[(((size_t)(nh*3+kt2)*4+qd)*128 + nf*16+ln)*8]);
      #pragma unroll
      for(int mf=0;mf<2;mf++)
        #pragma unroll
        for(int nf=0;nf<8;nf++)
          Oa[nh][mf][nf]=__builtin_amdgcn_mfma_f32_16x16x32_bf16(pa[mf],vf[nf],Oa[nh][mf][nf],0,0,0);
    }
  }
  __syncthreads();                        // barrier 4: Pb/KVf reads done, regions dead

  // ---- normalized O (bf16) -> Ol[128][264] ----
  #pragma unroll
  for(int nh=0;nh<2;nh++)
    #pragma unroll
    for(int mf=0;mf<2;mf++)
      #pragma unroll
      for(int r=0;r<4;r++){
        int ml = w*32+mf*16+qd*4+r;
        float inv = invr[ml];
        #pragma unroll
        for(int nf=0;nf<8;nf++)
          Ol[ml*264 + nh*128 + nf*16 + ln] = f2bf(Oa[nh][mf][nf][r]*inv);
      }
  __syncthreads();                        // barrier 5: O visible to all waves

  // ---- out = x + O @ wo^T + bo ; m = cl (this wave: w*64..w*64+63), n = px (128) ----
  f32x4 a2[4][8] = {};
  #pragma unroll 2
  for(int kt=0;kt<8;kt++){
    bf16x8 af2[4], bf2v[8];
    #pragma unroll
    for(int mf2=0;mf2<4;mf2++)
      af2[mf2] = ldfrag(woB + (size_t)(w*64+mf2*16+ln)*256 + kt*32 + qd*8);   // global, L2-hot
    #pragma unroll
    for(int nf2=0;nf2<8;nf2++)
      bf2v[nf2] = ldfrag(&Ol[(nf2*16+ln)*264 + kt*32 + qd*8]);
    #pragma unroll
    for(int mf2=0;mf2<4;mf2++)
      #pragma unroll
      for(int nf2=0;nf2<8;nf2++)
        a2[mf2][nf2] = __builtin_amdgcn_mfma_f32_16x16x32_bf16(af2[mf2], bf2v[nf2], a2[mf2][nf2],0,0,0);
  }
  #pragma unroll
  for(int mf2=0;mf2<4;mf2++)
    #pragma unroll
    for(int r=0;r<4;r++){
      int cl = w*64 + mf2*16 + qd*4 + r;
      float bias = bo[cl];
      #pragma unroll
      for(int nf2=0;nf2<8;nf2++){
        int px = p0 + nf2*16 + ln;
        size_t idx = ((size_t)(b*C_+cl))*HW_ + px;
        outp[idx] = x[idx] + a2[mf2][nf2][r] + bias;
      }
    }
}

extern "C" void kernel_launch(void* const* d_in, const int* in_sizes, int n_in,
                              void* d_out, int out_size, void* d_ws, size_t ws_size,
                              hipStream_t stream){
  const float* x      = (const float*)d_in[0];
  const float* ctx    = (const float*)d_in[1];
  const float* conv_w = (const float*)d_in[2];
  const float* conv_b = (const float*)d_in[3];
  const float* gnw    = (const float*)d_in[4];
  const float* gnb    = (const float*)d_in[5];
  const float* wq     = (const float*)d_in[6];
  const float* bq     = (const float*)d_in[7];
  const float* wk     = (const float*)d_in[8];
  const float* bk     = (const float*)d_in[9];
  const float* wv     = (const float*)d_in[10];
  const float* bv     = (const float*)d_in[11];
  const float* wo     = (const float*)d_in[12];
  const float* bo     = (const float*)d_in[13];
  char* ws = (char*)d_ws;
  u16* xpT  = (u16*)(ws + 0);            // 35,684,352 ; reused as q after conv
  u16* wBt  = (u16*)(ws + 35684352);     //  1,179,648
  u16* wqB  = (u16*)(ws + 36864000);     //    131,072
  u16* wkvB = (u16*)(ws + 36995072);     //    786,432
  u16* woB  = (u16*)(ws + 37781504);     //    131,072
  u16* ctxB = (u16*)(ws + 37912576);     //  1,892,352 (+74KB OOB read slack into hbuf)
  u16* hbuf = (u16*)(ws + 39804928);     // 33,554,432 (raw conv output)
  u16* kbv  = (u16*)(ws + 73359360);     //    630,784
  u16* vT   = (u16*)(ws + 73990144);     //    786,432
  float* stats = (float*)(ws + 108331008); // 2048
  u16* qb = xpT;
  float* outp = (float*)d_out;

  k_prep  <<<9106, 256, 0, stream>>>(x, xpT, conv_w, wq, wo, wk, wv, ctx, wBt, wqB, woB, wkvB, ctxB, stats);
  k_conv  <<<1024, 256, 0, stream>>>(xpT, wBt, conv_b, hbuf, stats);
  k_qgn   <<<512,  256, 0, stream>>>(hbuf, wqB, stats, gnw, gnb, bq, qb);
  k_kvproj<<<160,  256, 0, stream>>>(ctxB, wkvB, bk, bv, kbv, vT);
  k_attn  <<<512,  256, 0, stream>>>(qb, kbv, vT, woB, bo, x, outp);
}